// Round 1
// baseline (6478.614 us; speedup 1.0000x reference)
//
#include <hip/hip_runtime.h>
#include <math.h>

#define B_   128
#define S_   512
#define H_   1024
#define F_   512
#define V_   50000
#define OOV_ 50
#define EV_  (V_ + OOV_)   // 50050

// ---------------- generic fp32 GEMM: C[M,N] = A[M,K] @ W[N,K]^T + bias ----------------
__global__ __launch_bounds__(256)
void gemm_xwt(const float* __restrict__ A, const float* __restrict__ W,
              const float* __restrict__ bias, float* __restrict__ C,
              int M, int N, int K, int ldc)
{
  __shared__ float As[64][33];
  __shared__ float Ws[64][33];
  const int tid = threadIdx.x;
  const int tx = tid & 15, ty = tid >> 4;
  const int bm = blockIdx.y * 64, bn = blockIdx.x * 64;
  float acc[4][4] = {};
  for (int k0 = 0; k0 < K; k0 += 32) {
    for (int i = tid; i < 64 * 32; i += 256) {
      int r = i >> 5, c = i & 31;
      int m = bm + r;
      As[r][c] = (m < M) ? A[(size_t)m * K + k0 + c] : 0.f;
    }
    for (int i = tid; i < 64 * 32; i += 256) {
      int r = i >> 5, c = i & 31;
      int n = bn + r;
      Ws[r][c] = (n < N) ? W[(size_t)n * K + k0 + c] : 0.f;
    }
    __syncthreads();
#pragma unroll
    for (int kk = 0; kk < 32; ++kk) {
      float a4[4], w4[4];
#pragma unroll
      for (int i = 0; i < 4; i++) a4[i] = As[ty * 4 + i][kk];
#pragma unroll
      for (int j = 0; j < 4; j++) w4[j] = Ws[tx * 4 + j][kk];
#pragma unroll
      for (int i = 0; i < 4; i++)
#pragma unroll
        for (int j = 0; j < 4; j++)
          acc[i][j] = fmaf(a4[i], w4[j], acc[i][j]);
    }
    __syncthreads();
  }
#pragma unroll
  for (int i = 0; i < 4; i++) {
    int m = bm + ty * 4 + i;
    if (m >= M) continue;
#pragma unroll
    for (int j = 0; j < 4; j++) {
      int n = bn + tx * 4 + j;
      if (n < N) C[(size_t)m * ldc + n] = acc[i][j] + (bias ? bias[n] : 0.f);
    }
  }
}

// ------------- fused attention feature GEMM + tanh + dot(v) reduction -------------
// e_part[kt][bs] = sum_{n in kt-tile} tanh(enc[bs,:]·Wh[n,:] + sWs[b,n] + cov[bs]*wc[n] + ab[n]) * av[n]
__global__ __launch_bounds__(256)
void feat_e_kernel(const float* __restrict__ enc, const float* __restrict__ Wh,
                   const float* __restrict__ sWs, const float* __restrict__ cov,
                   const float* __restrict__ wc, const float* __restrict__ ab,
                   const float* __restrict__ av_, float* __restrict__ e_part)
{
  __shared__ float As[64][33];
  __shared__ float Ws[64][33];
  __shared__ float red[64][17];
  const int tid = threadIdx.x;
  const int tx = tid & 15, ty = tid >> 4;
  const int bs0 = blockIdx.x * 64;   // tile of 64 (b,s) rows; b constant per tile
  const int kt  = blockIdx.y;        // 0..15, 64 att-feature columns each
  const int kn0 = kt * 64;
  const int b   = bs0 / S_;
  float acc[4][4] = {};
  for (int k0 = 0; k0 < H_; k0 += 32) {
    for (int i = tid; i < 64 * 32; i += 256) {
      int r = i >> 5, c = i & 31;
      As[r][c] = enc[(size_t)(bs0 + r) * H_ + k0 + c];
    }
    for (int i = tid; i < 64 * 32; i += 256) {
      int r = i >> 5, c = i & 31;
      Ws[r][c] = Wh[(size_t)(kn0 + r) * H_ + k0 + c];
    }
    __syncthreads();
#pragma unroll
    for (int kk = 0; kk < 32; ++kk) {
      float a4[4], w4[4];
#pragma unroll
      for (int i = 0; i < 4; i++) a4[i] = As[ty * 4 + i][kk];
#pragma unroll
      for (int j = 0; j < 4; j++) w4[j] = Ws[tx * 4 + j][kk];
#pragma unroll
      for (int i = 0; i < 4; i++)
#pragma unroll
        for (int j = 0; j < 4; j++)
          acc[i][j] = fmaf(a4[i], w4[j], acc[i][j]);
    }
    __syncthreads();
  }
  // epilogue: tanh + scale by att_v, reduce over the 64 columns of this tile
#pragma unroll
  for (int i = 0; i < 4; i++) {
    int row = ty * 4 + i;
    float cv = cov[bs0 + row];
    float csum = 0.f;
#pragma unroll
    for (int j = 0; j < 4; j++) {
      int n = kn0 + tx * 4 + j;
      float val = acc[i][j] + sWs[(size_t)b * H_ + n] + cv * wc[n] + ab[n];
      csum += tanhf(val) * av_[n];
    }
    red[row][tx] = 0.f;  // placeholder (overwritten below)
    red[row][tx] = csum;
  }
  __syncthreads();
  if (tid < 64) {
    float s = 0.f;
#pragma unroll
    for (int t = 0; t < 16; t++) s += red[tid][t];
    e_part[(size_t)kt * (B_ * S_) + bs0 + tid] = s;
  }
}

// ---------------- softmax over S with mask + renorm; writes a and coverage ----------------
__global__ __launch_bounds__(512)
void softmax_a_kernel(const float* __restrict__ e_part, const float* __restrict__ mask,
                      const float* __restrict__ cov, float* __restrict__ a_ws,
                      float* __restrict__ out_a, float* __restrict__ out_cov)
{
  const int b = blockIdx.x;
  const int s = threadIdx.x;  // 512
  __shared__ float red[512];
  float e = 0.f;
  for (int kt = 0; kt < 16; ++kt) e += e_part[(size_t)kt * (B_ * S_) + b * S_ + s];
  red[s] = e;
  __syncthreads();
  for (int st = 256; st > 0; st >>= 1) {
    if (s < st) red[s] = fmaxf(red[s], red[s + st]);
    __syncthreads();
  }
  float mx = red[0];
  __syncthreads();
  float ex = expf(e - mx) * mask[b * S_ + s];
  red[s] = ex;
  __syncthreads();
  for (int st = 256; st > 0; st >>= 1) {
    if (s < st) red[s] += red[s + st];
    __syncthreads();
  }
  float a = ex / red[0];
  a_ws[b * S_ + s] = a;
  out_a[b * S_ + s] = a;
  out_cov[b * S_ + s] = cov[b * S_ + s] + a;
}

// ---------------- context[b,h] = sum_s a[b,s] * enc[b,s,h] ----------------
__global__ __launch_bounds__(256)
void context_kernel(const float* __restrict__ a_ws, const float* __restrict__ enc,
                    float* __restrict__ context)
{
  const int b = blockIdx.y;
  const int h = blockIdx.x * 256 + threadIdx.x;
  __shared__ float al[S_];
  for (int i = threadIdx.x; i < S_; i += 256) al[i] = a_ws[b * S_ + i];
  __syncthreads();
  float acc = 0.f;
  const float* ep = enc + (size_t)b * S_ * H_ + h;
  for (int s = 0; s < S_; ++s) acc = fmaf(al[s], ep[(size_t)s * H_], acc);
  context[b * H_ + h] = acc;
}

__global__ void xcat_kernel(const float* __restrict__ hidden, const float* __restrict__ context,
                            float* __restrict__ x_cat)
{
  int b = blockIdx.x;
  for (int j = threadIdx.x; j < 2 * H_; j += blockDim.x)
    x_cat[b * 2 * H_ + j] = (j < H_) ? hidden[b * H_ + j] : context[b * H_ + j - H_];
}

__global__ void gather_emb_kernel(const int* __restrict__ input, const float* __restrict__ emb,
                                  float* __restrict__ emb_x)
{
  int b = blockIdx.x;
  int row = input[b];
  for (int f = threadIdx.x; f < F_; f += 256)
    emb_x[b * F_ + f] = emb[(size_t)row * F_ + f];
}

__global__ void gru_kernel(const float* __restrict__ gi, const float* __restrict__ gh,
                           const float* __restrict__ h_att, float* __restrict__ h_new_ws,
                           float* __restrict__ out_h)
{
  int idx = blockIdx.x * 256 + threadIdx.x;  // B*H
  int b = idx / H_, h = idx % H_;
  float ir = gi[(size_t)b * 3 * H_ + h],          hr = gh[(size_t)b * 3 * H_ + h];
  float iz = gi[(size_t)b * 3 * H_ + H_ + h],     hz = gh[(size_t)b * 3 * H_ + H_ + h];
  float in_ = gi[(size_t)b * 3 * H_ + 2 * H_ + h], hn = gh[(size_t)b * 3 * H_ + 2 * H_ + h];
  float r = 1.f / (1.f + expf(-(ir + hr)));
  float z = 1.f / (1.f + expf(-(iz + hz)));
  float n = tanhf(in_ + r * hn);
  float ha = h_att[(size_t)b * H_ + h];
  float hv = (1.f - z) * n + z * ha;
  h_new_ws[idx] = hv;
  out_h[idx] = hv;
}

__global__ __launch_bounds__(256)
void pgen_kernel(const float* __restrict__ context, const float* __restrict__ h_new,
                 const float* __restrict__ emb_x, const float* __restrict__ wgen_w,
                 const float* __restrict__ wgen_b, float* __restrict__ pgen)
{
  int b = blockIdx.x;
  float acc = 0.f;
  for (int j = threadIdx.x; j < H_; j += 256) acc = fmaf(context[b * H_ + j], wgen_w[j], acc);
  for (int j = threadIdx.x; j < H_; j += 256) acc = fmaf(h_new[b * H_ + j], wgen_w[H_ + j], acc);
  for (int j = threadIdx.x; j < F_; j += 256) acc = fmaf(emb_x[b * F_ + j], wgen_w[2 * H_ + j], acc);
  __shared__ float red[256];
  red[threadIdx.x] = acc;
  __syncthreads();
  for (int st = 128; st > 0; st >>= 1) {
    if (threadIdx.x < st) red[threadIdx.x] += red[threadIdx.x + st];
    __syncthreads();
  }
  if (threadIdx.x == 0) {
    float p = 1.f / (1.f + expf(-(red[0] + wgen_b[0])));
    p = fminf(fmaxf(p, 0.001f), 0.999f);
    pgen[b] = p;
  }
}

__global__ __launch_bounds__(512)
void vstats_kernel(const float* __restrict__ logits, float* __restrict__ vmax,
                   float* __restrict__ vsum)
{
  int b = blockIdx.x;
  const float* row = logits + (size_t)b * EV_;
  __shared__ float red[512];
  float m = -1e30f;
  for (int v = threadIdx.x; v < V_; v += 512) m = fmaxf(m, row[v]);
  red[threadIdx.x] = m;
  __syncthreads();
  for (int st = 256; st > 0; st >>= 1) {
    if (threadIdx.x < st) red[threadIdx.x] = fmaxf(red[threadIdx.x], red[threadIdx.x + st]);
    __syncthreads();
  }
  m = red[0];
  __syncthreads();
  float ssum = 0.f;
  for (int v = threadIdx.x; v < V_; v += 512) ssum += expf(row[v] - m);
  red[threadIdx.x] = ssum;
  __syncthreads();
  for (int st = 256; st > 0; st >>= 1) {
    if (threadIdx.x < st) red[threadIdx.x] += red[threadIdx.x + st];
    __syncthreads();
  }
  if (threadIdx.x == 0) { vmax[b] = m; vsum[b] = red[0]; }
}

__global__ void final_kernel(float* __restrict__ out0, const float* __restrict__ vmax,
                             const float* __restrict__ vsum, const float* __restrict__ pgen)
{
  int b = blockIdx.y;
  int v = blockIdx.x * 256 + threadIdx.x;
  if (v >= EV_) return;
  float* row = out0 + (size_t)b * EV_;
  if (v < V_) row[v] = pgen[b] * expf(row[v] - vmax[b]) / vsum[b];
  else row[v] = 0.f;
}

__global__ void scatter_kernel(const int* __restrict__ ref2tgt, const float* __restrict__ a_ws,
                               const float* __restrict__ pgen, float* __restrict__ out0)
{
  int b = blockIdx.x;
  int s = threadIdx.x;  // 512
  float w = (1.f - pgen[b]) * a_ws[b * S_ + s];
  int t = ref2tgt[b * S_ + s];
  atomicAdd(&out0[(size_t)b * EV_ + t], w);
}

extern "C" void kernel_launch(void* const* d_in, const int* in_sizes, int n_in,
                              void* d_out, int out_size, void* d_ws, size_t ws_size,
                              hipStream_t stream)
{
  const int*   input   = (const int*)d_in[0];
  const float* hidden  = (const float*)d_in[1];
  const float* enc     = (const float*)d_in[2];
  const float* mask    = (const float*)d_in[3];
  /* d_in[4] len_oov unused by reference */
  const float* cov     = (const float*)d_in[5];
  const int*   ref2tgt = (const int*)d_in[6];
  const float* emb     = (const float*)d_in[7];
  const float* W_ih    = (const float*)d_in[8];
  const float* W_hh    = (const float*)d_in[9];
  const float* b_ih    = (const float*)d_in[10];
  const float* b_hh    = (const float*)d_in[11];
  const float* e2v1_w  = (const float*)d_in[12];
  const float* e2v1_b  = (const float*)d_in[13];
  const float* e2v2_w  = (const float*)d_in[14];
  const float* e2v2_b  = (const float*)d_in[15];
  const float* fc_w    = (const float*)d_in[16];
  const float* fc_b    = (const float*)d_in[17];
  const float* wgen_w  = (const float*)d_in[18];
  const float* wgen_b  = (const float*)d_in[19];
  const float* att_Wh  = (const float*)d_in[20];
  const float* att_Ws  = (const float*)d_in[21];
  const float* att_wc  = (const float*)d_in[22];
  const float* att_b   = (const float*)d_in[23];
  const float* att_v   = (const float*)d_in[24];

  float* ws = (float*)d_ws;
  float* sWs     = ws;                       // 131072
  float* e_part  = sWs + 131072;             // 16*65536
  float* a_ws    = e_part + 16 * 65536;      // 65536
  float* context = a_ws + 65536;             // 131072
  float* x_cat   = context + 131072;         // 262144
  float* h_att   = x_cat + 262144;           // 131072
  float* emb_x   = h_att + 131072;           // 65536
  float* gi      = emb_x + 65536;            // 393216
  float* gh      = gi + 393216;              // 393216
  float* h_new   = gh + 393216;              // 131072
  float* out1    = h_new + 131072;           // 65536
  float* pgen    = out1 + 65536;             // 128
  float* vmax    = pgen + 128;               // 128
  float* vsum    = vmax + 128;               // 128

  float* out0    = (float*)d_out;                 // final [B, EV]
  float* out_h   = out0 + (size_t)B_ * EV_;       // h_new [1,B,H]
  float* out_cov = out_h + (size_t)B_ * H_;       // coverage_new [B,S]
  float* out_a   = out_cov + (size_t)B_ * S_;     // a [B,S]

  gather_emb_kernel<<<B_, 256, 0, stream>>>(input, emb, emb_x);
  // sWs = s @ att_Ws^T
  gemm_xwt<<<dim3(16, 2), 256, 0, stream>>>(hidden, att_Ws, nullptr, sWs, B_, H_, H_, H_);
  // fused attention feature GEMM + tanh + v-dot partial reduction
  feat_e_kernel<<<dim3(1024, 16), 256, 0, stream>>>(enc, att_Wh, sWs, cov, att_wc, att_b, att_v, e_part);
  softmax_a_kernel<<<B_, 512, 0, stream>>>(e_part, mask, cov, a_ws, out_a, out_cov);
  context_kernel<<<dim3(H_ / 256, B_), 256, 0, stream>>>(a_ws, enc, context);
  xcat_kernel<<<B_, 256, 0, stream>>>(hidden, context, x_cat);
  // h_att = [s, context] @ fc_w^T + fc_b
  gemm_xwt<<<dim3(16, 2), 256, 0, stream>>>(x_cat, fc_w, fc_b, h_att, B_, H_, 2 * H_, H_);
  // GRU gates
  gemm_xwt<<<dim3(48, 2), 256, 0, stream>>>(emb_x, W_ih, b_ih, gi, B_, 3 * H_, F_, 3 * H_);
  gemm_xwt<<<dim3(48, 2), 256, 0, stream>>>(h_att, W_hh, b_hh, gh, B_, 3 * H_, H_, 3 * H_);
  gru_kernel<<<(B_ * H_) / 256, 256, 0, stream>>>(gi, gh, h_att, h_new, out_h);
  // vocab head
  gemm_xwt<<<dim3(8, 2), 256, 0, stream>>>(h_new, e2v1_w, e2v1_b, out1, B_, F_, H_, F_);
  gemm_xwt<<<dim3(782, 2), 256, 0, stream>>>(out1, e2v2_w, e2v2_b, out0, B_, V_, F_, EV_);
  pgen_kernel<<<B_, 256, 0, stream>>>(context, h_new, emb_x, wgen_w, wgen_b, pgen);
  vstats_kernel<<<B_, 512, 0, stream>>>(out0, vmax, vsum);
  final_kernel<<<dim3((EV_ + 255) / 256, B_), 256, 0, stream>>>(out0, vmax, vsum, pgen);
  scatter_kernel<<<B_, 512, 0, stream>>>(ref2tgt, a_ws, pgen, out0);
}

// Round 2
// 1873.159 us; speedup vs baseline: 3.4587x; 3.4587x over previous
//
#include <hip/hip_runtime.h>
#include <math.h>

#define B_   128
#define S_   512
#define H_   1024
#define F_   512
#define V_   50000
#define OOV_ 50
#define EV_  (V_ + OOV_)   // 50050

#define BM 128
#define BN 128
#define BK 64

typedef __attribute__((ext_vector_type(8))) __bf16 bf16x8;
typedef __attribute__((ext_vector_type(4))) float  f32x4;

__device__ __forceinline__ void gload_lds16(const void* g, void* lds) {
  __builtin_amdgcn_global_load_lds(
      (const __attribute__((address_space(1))) unsigned int*)g,
      (__attribute__((address_space(3))) unsigned int*)lds, 16, 0, 0);
}

// ---------------- fp32 -> bf16 cast, vectorized ----------------
__global__ __launch_bounds__(256)
void f32_to_bf16_kernel(const float* __restrict__ in, __bf16* __restrict__ out, int n)
{
  for (size_t i = ((size_t)blockIdx.x * 256 + threadIdx.x) * 8; i < (size_t)n;
       i += (size_t)gridDim.x * 256 * 8) {
    float4 a = *(const float4*)(in + i);
    float4 b = *(const float4*)(in + i + 4);
    bf16x8 o;
    o[0] = (__bf16)a.x; o[1] = (__bf16)a.y; o[2] = (__bf16)a.z; o[3] = (__bf16)a.w;
    o[4] = (__bf16)b.x; o[5] = (__bf16)b.y; o[6] = (__bf16)b.z; o[7] = (__bf16)b.w;
    *(bf16x8*)(out + i) = o;
  }
}

// ---------------- generic fp32 GEMM (small ops): C[M,N] = A[M,K] @ W[N,K]^T + bias ----------------
__global__ __launch_bounds__(256)
void gemm_xwt(const float* __restrict__ A, const float* __restrict__ W,
              const float* __restrict__ bias, float* __restrict__ C,
              int M, int N, int K, int ldc)
{
  __shared__ float As[64][33];
  __shared__ float Ws[64][33];
  const int tid = threadIdx.x;
  const int tx = tid & 15, ty = tid >> 4;
  const int bm = blockIdx.y * 64, bn = blockIdx.x * 64;
  float acc[4][4] = {};
  for (int k0 = 0; k0 < K; k0 += 32) {
    for (int i = tid; i < 64 * 32; i += 256) {
      int r = i >> 5, c = i & 31;
      int m = bm + r;
      As[r][c] = (m < M) ? A[(size_t)m * K + k0 + c] : 0.f;
    }
    for (int i = tid; i < 64 * 32; i += 256) {
      int r = i >> 5, c = i & 31;
      int n = bn + r;
      Ws[r][c] = (n < N) ? W[(size_t)n * K + k0 + c] : 0.f;
    }
    __syncthreads();
#pragma unroll
    for (int kk = 0; kk < 32; ++kk) {
      float a4[4], w4[4];
#pragma unroll
      for (int i = 0; i < 4; i++) a4[i] = As[ty * 4 + i][kk];
#pragma unroll
      for (int j = 0; j < 4; j++) w4[j] = Ws[tx * 4 + j][kk];
#pragma unroll
      for (int i = 0; i < 4; i++)
#pragma unroll
        for (int j = 0; j < 4; j++)
          acc[i][j] = fmaf(a4[i], w4[j], acc[i][j]);
    }
    __syncthreads();
  }
#pragma unroll
  for (int i = 0; i < 4; i++) {
    int m = bm + ty * 4 + i;
    if (m >= M) continue;
#pragma unroll
    for (int j = 0; j < 4; j++) {
      int n = bn + tx * 4 + j;
      if (n < N) C[(size_t)m * ldc + n] = acc[i][j] + (bias ? bias[n] : 0.f);
    }
  }
}

// ------------- MFMA attention feature GEMM + tanh + dot(v) reduction -------------
// e_part[nt][bs] = sum_{n in nt-tile of 128} tanh(enc[bs,:]·Wh[n,:] + sWs[b,n] + cov[bs]*wc[n] + ab[n]) * av[n]
__global__ __launch_bounds__(256)
void feat_mfma_kernel(const __bf16* __restrict__ enc, const __bf16* __restrict__ Wh,
                      const float* __restrict__ sWs, const float* __restrict__ cov,
                      const float* __restrict__ wcv, const float* __restrict__ ab,
                      const float* __restrict__ av_, float* __restrict__ e_part)
{
  __shared__ __attribute__((aligned(16))) __bf16 As[BM * BK];
  __shared__ __attribute__((aligned(16))) __bf16 Bs[BN * BK];
  __shared__ float red[BM][2];
  const int tid  = threadIdx.x;
  const int lane = tid & 63, wid = tid >> 6;
  const int wr = wid >> 1, wcc = wid & 1;
  const int bs0 = blockIdx.x * BM;
  const int n0  = blockIdx.y * BN;
  const int b   = bs0 / S_;

  f32x4 acc[4][4];
#pragma unroll
  for (int i = 0; i < 4; i++)
#pragma unroll
    for (int j = 0; j < 4; j++) acc[i][j] = (f32x4){0.f, 0.f, 0.f, 0.f};

  for (int k0 = 0; k0 < H_; k0 += BK) {
    // stage A,B tiles: linear LDS dest, inverse-swizzled per-lane global source
#pragma unroll
    for (int p = 0; p < 4; ++p) {
      int off = p * 4096 + tid * 16;          // dest byte offset
      int r = off >> 7, cb = off & 127;       // row, col-byte within row (128B rows)
      int scb = cb ^ ((r & 7) << 4);          // source col-byte (XOR swizzle)
      gload_lds16(enc + (size_t)(bs0 + r) * H_ + k0 + (scb >> 1), (char*)As + off);
      gload_lds16(Wh  + (size_t)(n0 + r) * H_ + k0 + (scb >> 1), (char*)Bs + off);
    }
    __syncthreads();  // drains vmcnt before barrier

    bf16x8 af[4][2], bf[4][2];
#pragma unroll
    for (int m = 0; m < 4; ++m) {
      int row = wr * 64 + m * 16 + (lane & 15);
      int swz = (row & 7) << 4;
#pragma unroll
      for (int kk = 0; kk < 2; ++kk) {
        int kb = kk * 64 + ((lane >> 4) << 4);
        af[m][kk] = *(const bf16x8*)((const char*)As + row * 128 + (kb ^ swz));
      }
    }
#pragma unroll
    for (int n = 0; n < 4; ++n) {
      int row = wcc * 64 + n * 16 + (lane & 15);
      int swz = (row & 7) << 4;
#pragma unroll
      for (int kk = 0; kk < 2; ++kk) {
        int kb = kk * 64 + ((lane >> 4) << 4);
        bf[n][kk] = *(const bf16x8*)((const char*)Bs + row * 128 + (kb ^ swz));
      }
    }
#pragma unroll
    for (int m = 0; m < 4; ++m)
#pragma unroll
      for (int n = 0; n < 4; ++n)
#pragma unroll
        for (int kk = 0; kk < 2; ++kk)
          acc[m][n] = __builtin_amdgcn_mfma_f32_16x16x32_bf16(af[m][kk], bf[n][kk], acc[m][n], 0, 0, 0);
    __syncthreads();
  }

  // epilogue: +sWs +cov*wc +b, tanh, *av, reduce over the 128 columns of this tile
  float rowsum[4][4];
#pragma unroll
  for (int m = 0; m < 4; m++)
#pragma unroll
    for (int j = 0; j < 4; j++) rowsum[m][j] = 0.f;

#pragma unroll
  for (int m = 0; m < 4; ++m) {
#pragma unroll
    for (int n = 0; n < 4; ++n) {
      int col_g = n0 + wcc * 64 + n * 16 + (lane & 15);
      float sw = sWs[(size_t)b * H_ + col_g];
      float wc_n = wcv[col_g], ab_n = ab[col_g], av_n = av_[col_g];
#pragma unroll
      for (int j = 0; j < 4; ++j) {
        int row_l = wr * 64 + m * 16 + ((lane >> 4) << 2) + j;
        float val = acc[m][n][j] + sw + cov[bs0 + row_l] * wc_n + ab_n;
        rowsum[m][j] += tanhf(val) * av_n;
      }
    }
  }
  // sum across the 16 lanes holding different columns of the same row
#pragma unroll
  for (int m = 0; m < 4; ++m)
#pragma unroll
    for (int j = 0; j < 4; ++j) {
      float v = rowsum[m][j];
      v += __shfl_xor(v, 1);
      v += __shfl_xor(v, 2);
      v += __shfl_xor(v, 4);
      v += __shfl_xor(v, 8);
      rowsum[m][j] = v;
    }
  if ((lane & 15) == 0) {
#pragma unroll
    for (int m = 0; m < 4; ++m)
#pragma unroll
      for (int j = 0; j < 4; ++j)
        red[wr * 64 + m * 16 + ((lane >> 4) << 2) + j][wcc] = rowsum[m][j];
  }
  __syncthreads();
  if (tid < BM)
    e_part[(size_t)blockIdx.y * (B_ * S_) + bs0 + tid] = red[tid][0] + red[tid][1];
}

// ------------- MFMA logits GEMM: out0[b, v] = out1[b,:]·e2v2_w[v,:] + bias[v] -------------
__global__ __launch_bounds__(256)
void logits_mfma_kernel(const __bf16* __restrict__ A, const float* __restrict__ W,
                        const float* __restrict__ bias, float* __restrict__ out0)
{
  __shared__ __attribute__((aligned(16))) __bf16 As[BM * BK];
  __shared__ __attribute__((aligned(16))) __bf16 Bs[BN * BK];
  const int tid  = threadIdx.x;
  const int lane = tid & 63, wid = tid >> 6;
  const int wr = wid >> 1, wcc = wid & 1;
  const int n0 = blockIdx.x * BN;

  f32x4 acc[4][4];
#pragma unroll
  for (int i = 0; i < 4; i++)
#pragma unroll
    for (int j = 0; j < 4; j++) acc[i][j] = (f32x4){0.f, 0.f, 0.f, 0.f};

  for (int k0 = 0; k0 < F_; k0 += BK) {
    // A: async global->LDS (bf16, 128x64)
#pragma unroll
    for (int p = 0; p < 4; ++p) {
      int off = p * 4096 + tid * 16;
      int r = off >> 7, cb = off & 127;
      int scb = cb ^ ((r & 7) << 4);
      gload_lds16(A + (size_t)r * F_ + k0 + (scb >> 1), (char*)As + off);
    }
    // B: fp32 load + convert + swizzled ds_write (W rows clamped at V-1 for the tail tile)
#pragma unroll
    for (int p = 0; p < 8; ++p) {
      int idx = p * 1024 + tid * 4;           // element index in 128x64 tile
      int r = idx >> 6, c = idx & 63;
      int row_g = n0 + r; if (row_g >= V_) row_g = V_ - 1;
      float4 f = *(const float4*)(W + (size_t)row_g * F_ + k0 + c);
      union { __bf16 h[4]; uint2 u; } t;
      t.h[0] = (__bf16)f.x; t.h[1] = (__bf16)f.y; t.h[2] = (__bf16)f.z; t.h[3] = (__bf16)f.w;
      int cb = c * 2;
      *(uint2*)((char*)Bs + r * 128 + (cb ^ ((r & 7) << 4))) = t.u;
    }
    __syncthreads();

    bf16x8 af[4][2], bf[4][2];
#pragma unroll
    for (int m = 0; m < 4; ++m) {
      int row = wr * 64 + m * 16 + (lane & 15);
      int swz = (row & 7) << 4;
#pragma unroll
      for (int kk = 0; kk < 2; ++kk) {
        int kb = kk * 64 + ((lane >> 4) << 4);
        af[m][kk] = *(const bf16x8*)((const char*)As + row * 128 + (kb ^ swz));
      }
    }
#pragma unroll
    for (int n = 0; n < 4; ++n) {
      int row = wcc * 64 + n * 16 + (lane & 15);
      int swz = (row & 7) << 4;
#pragma unroll
      for (int kk = 0; kk < 2; ++kk) {
        int kb = kk * 64 + ((lane >> 4) << 4);
        bf[n][kk] = *(const bf16x8*)((const char*)Bs + row * 128 + (kb ^ swz));
      }
    }
#pragma unroll
    for (int m = 0; m < 4; ++m)
#pragma unroll
      for (int n = 0; n < 4; ++n)
#pragma unroll
        for (int kk = 0; kk < 2; ++kk)
          acc[m][n] = __builtin_amdgcn_mfma_f32_16x16x32_bf16(af[m][kk], bf[n][kk], acc[m][n], 0, 0, 0);
    __syncthreads();
  }

#pragma unroll
  for (int m = 0; m < 4; ++m) {
#pragma unroll
    for (int n = 0; n < 4; ++n) {
      int col_g = n0 + wcc * 64 + n * 16 + (lane & 15);
      if (col_g >= V_) continue;
      float bv = bias[col_g];
#pragma unroll
      for (int j = 0; j < 4; ++j) {
        int row = wr * 64 + m * 16 + ((lane >> 4) << 2) + j;  // row < 128 == B_
        out0[(size_t)row * EV_ + col_g] = acc[m][n][j] + bv;
      }
    }
  }
}

// ---------------- softmax over S with mask + renorm; writes a and coverage ----------------
__global__ __launch_bounds__(512)
void softmax_a_kernel(const float* __restrict__ e_part, const float* __restrict__ mask,
                      const float* __restrict__ cov, float* __restrict__ a_ws,
                      float* __restrict__ out_a, float* __restrict__ out_cov)
{
  const int b = blockIdx.x;
  const int s = threadIdx.x;  // 512
  __shared__ float red[512];
  float e = 0.f;
  for (int kt = 0; kt < 8; ++kt) e += e_part[(size_t)kt * (B_ * S_) + b * S_ + s];
  red[s] = e;
  __syncthreads();
  for (int st = 256; st > 0; st >>= 1) {
    if (s < st) red[s] = fmaxf(red[s], red[s + st]);
    __syncthreads();
  }
  float mx = red[0];
  __syncthreads();
  float ex = expf(e - mx) * mask[b * S_ + s];
  red[s] = ex;
  __syncthreads();
  for (int st = 256; st > 0; st >>= 1) {
    if (s < st) red[s] += red[s + st];
    __syncthreads();
  }
  float a = ex / red[0];
  a_ws[b * S_ + s] = a;
  out_a[b * S_ + s] = a;
  out_cov[b * S_ + s] = cov[b * S_ + s] + a;
}

// ---------------- context[b,h] = sum_s a[b,s] * enc[b,s,h] ----------------
__global__ __launch_bounds__(256)
void context_kernel(const float* __restrict__ a_ws, const float* __restrict__ enc,
                    float* __restrict__ context)
{
  const int b = blockIdx.y;
  const int h = blockIdx.x * 256 + threadIdx.x;
  __shared__ float al[S_];
  for (int i = threadIdx.x; i < S_; i += 256) al[i] = a_ws[b * S_ + i];
  __syncthreads();
  float acc = 0.f;
  const float* ep = enc + (size_t)b * S_ * H_ + h;
  for (int s = 0; s < S_; ++s) acc = fmaf(al[s], ep[(size_t)s * H_], acc);
  context[b * H_ + h] = acc;
}

__global__ void xcat_kernel(const float* __restrict__ hidden, const float* __restrict__ context,
                            float* __restrict__ x_cat)
{
  int b = blockIdx.x;
  for (int j = threadIdx.x; j < 2 * H_; j += blockDim.x)
    x_cat[b * 2 * H_ + j] = (j < H_) ? hidden[b * H_ + j] : context[b * H_ + j - H_];
}

__global__ void gather_emb_kernel(const int* __restrict__ input, const float* __restrict__ emb,
                                  float* __restrict__ emb_x)
{
  int b = blockIdx.x;
  int row = input[b];
  for (int f = threadIdx.x; f < F_; f += 256)
    emb_x[b * F_ + f] = emb[(size_t)row * F_ + f];
}

__global__ void gru_kernel(const float* __restrict__ gi, const float* __restrict__ gh,
                           const float* __restrict__ h_att, float* __restrict__ h_new_ws,
                           float* __restrict__ out_h)
{
  int idx = blockIdx.x * 256 + threadIdx.x;  // B*H
  int b = idx / H_, h = idx % H_;
  float ir = gi[(size_t)b * 3 * H_ + h],           hr = gh[(size_t)b * 3 * H_ + h];
  float iz = gi[(size_t)b * 3 * H_ + H_ + h],      hz = gh[(size_t)b * 3 * H_ + H_ + h];
  float in_ = gi[(size_t)b * 3 * H_ + 2 * H_ + h], hn = gh[(size_t)b * 3 * H_ + 2 * H_ + h];
  float r = 1.f / (1.f + expf(-(ir + hr)));
  float z = 1.f / (1.f + expf(-(iz + hz)));
  float n = tanhf(in_ + r * hn);
  float ha = h_att[(size_t)b * H_ + h];
  float hv = (1.f - z) * n + z * ha;
  h_new_ws[idx] = hv;
  out_h[idx] = hv;
}

__global__ __launch_bounds__(256)
void pgen_kernel(const float* __restrict__ context, const float* __restrict__ h_new,
                 const float* __restrict__ emb_x, const float* __restrict__ wgen_w,
                 const float* __restrict__ wgen_b, float* __restrict__ pgen)
{
  int b = blockIdx.x;
  float acc = 0.f;
  for (int j = threadIdx.x; j < H_; j += 256) acc = fmaf(context[b * H_ + j], wgen_w[j], acc);
  for (int j = threadIdx.x; j < H_; j += 256) acc = fmaf(h_new[b * H_ + j], wgen_w[H_ + j], acc);
  for (int j = threadIdx.x; j < F_; j += 256) acc = fmaf(emb_x[b * F_ + j], wgen_w[2 * H_ + j], acc);
  __shared__ float red[256];
  red[threadIdx.x] = acc;
  __syncthreads();
  for (int st = 128; st > 0; st >>= 1) {
    if (threadIdx.x < st) red[threadIdx.x] += red[threadIdx.x + st];
    __syncthreads();
  }
  if (threadIdx.x == 0) {
    float p = 1.f / (1.f + expf(-(red[0] + wgen_b[0])));
    p = fminf(fmaxf(p, 0.001f), 0.999f);
    pgen[b] = p;
  }
}

__global__ __launch_bounds__(512)
void vstats_kernel(const float* __restrict__ logits, float* __restrict__ vmax,
                   float* __restrict__ vsum)
{
  int b = blockIdx.x;
  const float* row = logits + (size_t)b * EV_;
  __shared__ float red[512];
  float m = -1e30f;
  for (int v = threadIdx.x; v < V_; v += 512) m = fmaxf(m, row[v]);
  red[threadIdx.x] = m;
  __syncthreads();
  for (int st = 256; st > 0; st >>= 1) {
    if (threadIdx.x < st) red[threadIdx.x] = fmaxf(red[threadIdx.x], red[threadIdx.x + st]);
    __syncthreads();
  }
  m = red[0];
  __syncthreads();
  float ssum = 0.f;
  for (int v = threadIdx.x; v < V_; v += 512) ssum += expf(row[v] - m);
  red[threadIdx.x] = ssum;
  __syncthreads();
  for (int st = 256; st > 0; st >>= 1) {
    if (threadIdx.x < st) red[threadIdx.x] += red[threadIdx.x + st];
    __syncthreads();
  }
  if (threadIdx.x == 0) { vmax[b] = m; vsum[b] = red[0]; }
}

__global__ void final_kernel(float* __restrict__ out0, const float* __restrict__ vmax,
                             const float* __restrict__ vsum, const float* __restrict__ pgen)
{
  int b = blockIdx.y;
  int v = blockIdx.x * 256 + threadIdx.x;
  if (v >= EV_) return;
  float* row = out0 + (size_t)b * EV_;
  if (v < V_) row[v] = pgen[b] * expf(row[v] - vmax[b]) / vsum[b];
  else row[v] = 0.f;
}

__global__ void scatter_kernel(const int* __restrict__ ref2tgt, const float* __restrict__ a_ws,
                               const float* __restrict__ pgen, float* __restrict__ out0)
{
  int b = blockIdx.x;
  int s = threadIdx.x;  // 512
  float w = (1.f - pgen[b]) * a_ws[b * S_ + s];
  int t = ref2tgt[b * S_ + s];
  atomicAdd(&out0[(size_t)b * EV_ + t], w);
}

extern "C" void kernel_launch(void* const* d_in, const int* in_sizes, int n_in,
                              void* d_out, int out_size, void* d_ws, size_t ws_size,
                              hipStream_t stream)
{
  const int*   input   = (const int*)d_in[0];
  const float* hidden  = (const float*)d_in[1];
  const float* enc     = (const float*)d_in[2];
  const float* mask    = (const float*)d_in[3];
  const float* cov     = (const float*)d_in[5];
  const int*   ref2tgt = (const int*)d_in[6];
  const float* emb     = (const float*)d_in[7];
  const float* W_ih    = (const float*)d_in[8];
  const float* W_hh    = (const float*)d_in[9];
  const float* b_ih    = (const float*)d_in[10];
  const float* b_hh    = (const float*)d_in[11];
  const float* e2v1_w  = (const float*)d_in[12];
  const float* e2v1_b  = (const float*)d_in[13];
  const float* e2v2_w  = (const float*)d_in[14];
  const float* e2v2_b  = (const float*)d_in[15];
  const float* fc_w    = (const float*)d_in[16];
  const float* fc_b    = (const float*)d_in[17];
  const float* wgen_w  = (const float*)d_in[18];
  const float* wgen_b  = (const float*)d_in[19];
  const float* att_Wh  = (const float*)d_in[20];
  const float* att_Ws  = (const float*)d_in[21];
  const float* att_wc  = (const float*)d_in[22];
  const float* att_b   = (const float*)d_in[23];
  const float* att_v   = (const float*)d_in[24];

  char* w = (char*)d_ws;
  __bf16* enc_h  = (__bf16*)w;  w += (size_t)B_ * S_ * H_ * 2;   // 134.2 MB
  __bf16* Wh_h   = (__bf16*)w;  w += (size_t)H_ * H_ * 2;        // 2 MB
  __bf16* out1_h = (__bf16*)w;  w += (size_t)B_ * F_ * 2;        // 128 KB
  float* sWs     = (float*)w;   w += (size_t)B_ * H_ * 4;
  float* e_part  = (float*)w;   w += (size_t)8 * B_ * S_ * 4;
  float* a_ws    = (float*)w;   w += (size_t)B_ * S_ * 4;
  float* context = (float*)w;   w += (size_t)B_ * H_ * 4;
  float* x_cat   = (float*)w;   w += (size_t)B_ * 2 * H_ * 4;
  float* h_att   = (float*)w;   w += (size_t)B_ * H_ * 4;
  float* emb_x   = (float*)w;   w += (size_t)B_ * F_ * 4;
  float* gi      = (float*)w;   w += (size_t)B_ * 3 * H_ * 4;
  float* gh      = (float*)w;   w += (size_t)B_ * 3 * H_ * 4;
  float* h_new   = (float*)w;   w += (size_t)B_ * H_ * 4;
  float* out1    = (float*)w;   w += (size_t)B_ * F_ * 4;
  float* pgen    = (float*)w;   w += 128 * 4;
  float* vmax    = (float*)w;   w += 128 * 4;
  float* vsum    = (float*)w;   w += 128 * 4;

  float* out0    = (float*)d_out;                 // final [B, EV]
  float* out_h   = out0 + (size_t)B_ * EV_;       // h_new [1,B,H]
  float* out_cov = out_h + (size_t)B_ * H_;       // coverage_new [B,S]
  float* out_a   = out_cov + (size_t)B_ * S_;     // a [B,S]

  // bf16 casts (enc is the big one: 134 MB -> fits L3 for the 8 N-tile re-reads)
  f32_to_bf16_kernel<<<4096, 256, 0, stream>>>(enc, enc_h, B_ * S_ * H_);
  f32_to_bf16_kernel<<<512, 256, 0, stream>>>(att_Wh, Wh_h, H_ * H_);

  gather_emb_kernel<<<B_, 256, 0, stream>>>(input, emb, emb_x);
  gemm_xwt<<<dim3(16, 2), 256, 0, stream>>>(hidden, att_Ws, nullptr, sWs, B_, H_, H_, H_);

  feat_mfma_kernel<<<dim3(B_ * S_ / BM, H_ / BN), 256, 0, stream>>>(
      enc_h, Wh_h, sWs, cov, att_wc, att_b, att_v, e_part);
  softmax_a_kernel<<<B_, 512, 0, stream>>>(e_part, mask, cov, a_ws, out_a, out_cov);
  context_kernel<<<dim3(H_ / 256, B_), 256, 0, stream>>>(a_ws, enc, context);
  xcat_kernel<<<B_, 256, 0, stream>>>(hidden, context, x_cat);
  gemm_xwt<<<dim3(16, 2), 256, 0, stream>>>(x_cat, fc_w, fc_b, h_att, B_, H_, 2 * H_, H_);
  gemm_xwt<<<dim3(48, 2), 256, 0, stream>>>(emb_x, W_ih, b_ih, gi, B_, 3 * H_, F_, 3 * H_);
  gemm_xwt<<<dim3(48, 2), 256, 0, stream>>>(h_att, W_hh, b_hh, gh, B_, 3 * H_, H_, 3 * H_);
  gru_kernel<<<(B_ * H_) / 256, 256, 0, stream>>>(gi, gh, h_att, h_new, out_h);

  gemm_xwt<<<dim3(8, 2), 256, 0, stream>>>(h_new, e2v1_w, e2v1_b, out1, B_, F_, H_, F_);
  f32_to_bf16_kernel<<<32, 256, 0, stream>>>(out1, out1_h, B_ * F_);
  logits_mfma_kernel<<<dim3((V_ + BN - 1) / BN), 256, 0, stream>>>(out1_h, e2v2_w, e2v2_b, out0);

  pgen_kernel<<<B_, 256, 0, stream>>>(context, h_new, emb_x, wgen_w, wgen_b, pgen);
  vstats_kernel<<<B_, 512, 0, stream>>>(out0, vmax, vsum);
  final_kernel<<<dim3((EV_ + 255) / 256, B_), 256, 0, stream>>>(out0, vmax, vsum, pgen);
  scatter_kernel<<<B_, 512, 0, stream>>>(ref2tgt, a_ws, pgen, out0);
}

// Round 3
// 572.726 us; speedup vs baseline: 11.3119x; 3.2706x over previous
//
#include <hip/hip_runtime.h>
#include <math.h>

#define B_   128
#define S_   512
#define H_   1024
#define F_   512
#define V_   50000
#define OOV_ 50
#define EV_  (V_ + OOV_)   // 50050

#define BM 128
#define BN 128
#define BK 64

typedef __attribute__((ext_vector_type(8))) __bf16 bf16x8;
typedef __attribute__((ext_vector_type(4))) float  f32x4;

__device__ __forceinline__ void gload_lds16(const void* g, void* lds) {
  __builtin_amdgcn_global_load_lds(
      (const __attribute__((address_space(1))) unsigned int*)g,
      (__attribute__((address_space(3))) unsigned int*)lds, 16, 0, 0);
}

// ---------------- fp32 -> bf16 cast, vectorized ----------------
__global__ __launch_bounds__(256)
void f32_to_bf16_kernel(const float* __restrict__ in, __bf16* __restrict__ out, int n)
{
  for (size_t i = ((size_t)blockIdx.x * 256 + threadIdx.x) * 8; i < (size_t)n;
       i += (size_t)gridDim.x * 256 * 8) {
    float4 a = *(const float4*)(in + i);
    float4 b = *(const float4*)(in + i + 4);
    bf16x8 o;
    o[0] = (__bf16)a.x; o[1] = (__bf16)a.y; o[2] = (__bf16)a.z; o[3] = (__bf16)a.w;
    o[4] = (__bf16)b.x; o[5] = (__bf16)b.y; o[6] = (__bf16)b.z; o[7] = (__bf16)b.w;
    *(bf16x8*)(out + i) = o;
  }
}

// ---------------- split-K fp32 GEMM: partial[p][m][n] over K-slice of KS ----------------
// C[M=128, N] = A[128, K] @ W[N, K]^T.  grid = (N/32, K/KS). 128x32x64 fragment per K-step.
__global__ __launch_bounds__(256)
void gemm_splitk(const float* __restrict__ A, const float* __restrict__ W,
                 float* __restrict__ partial, int N, int K, int KS)
{
  __shared__ float As[128 * 68];   // pad 64->68: float4-aligned rows, conflict-free
  __shared__ float Ws[32 * 68];
  const int tid = threadIdx.x;
  const int n0 = blockIdx.x * 32;
  const int p  = blockIdx.y;
  const int tx = tid & 7, ty = tid >> 3;
  const int lr = tid >> 4, lc4 = (tid & 15) * 4;
  float acc[4][4] = {};
  const int kend = p * KS + KS;
  for (int k0 = p * KS; k0 < kend; k0 += 64) {
#pragma unroll
    for (int pp = 0; pp < 8; ++pp) {
      float4 v = *(const float4*)(A + (size_t)(pp * 16 + lr) * K + k0 + lc4);
      *(float4*)(As + (pp * 16 + lr) * 68 + lc4) = v;
    }
#pragma unroll
    for (int pp = 0; pp < 2; ++pp) {
      float4 v = *(const float4*)(W + (size_t)(n0 + pp * 16 + lr) * K + k0 + lc4);
      *(float4*)(Ws + (pp * 16 + lr) * 68 + lc4) = v;
    }
    __syncthreads();
#pragma unroll
    for (int kk = 0; kk < 16; ++kk) {
      float4 av[4], wv[4];
#pragma unroll
      for (int i = 0; i < 4; i++) av[i] = *(const float4*)(As + (ty * 4 + i) * 68 + kk * 4);
#pragma unroll
      for (int j = 0; j < 4; j++) wv[j] = *(const float4*)(Ws + (tx * 4 + j) * 68 + kk * 4);
#pragma unroll
      for (int i = 0; i < 4; i++)
#pragma unroll
        for (int j = 0; j < 4; j++) {
          acc[i][j] = fmaf(av[i].x, wv[j].x, acc[i][j]);
          acc[i][j] = fmaf(av[i].y, wv[j].y, acc[i][j]);
          acc[i][j] = fmaf(av[i].z, wv[j].z, acc[i][j]);
          acc[i][j] = fmaf(av[i].w, wv[j].w, acc[i][j]);
        }
    }
    __syncthreads();
  }
#pragma unroll
  for (int i = 0; i < 4; i++)
#pragma unroll
    for (int j = 0; j < 4; j++)
      partial[((size_t)p * 128 + ty * 4 + i) * N + n0 + tx * 4 + j] = acc[i][j];
}

// C[idx] = bias[n] + sum_p partial[p][idx]   (idx over 128*N)
__global__ __launch_bounds__(256)
void reduce_partial(const float* __restrict__ partial, const float* __restrict__ bias,
                    float* __restrict__ C, int N, int P)
{
  int idx = blockIdx.x * 256 + threadIdx.x;
  int n = idx % N;
  float s = bias ? bias[n] : 0.f;
  for (int p = 0; p < P; ++p) s += partial[(size_t)p * 128 * N + idx];
  C[idx] = s;
}

// ------------- MFMA attention feature GEMM + tanh + dot(v) reduction -------------
// e_part[nt][bs] = sum_{n in nt-tile of 128} tanh(enc[bs,:]·Wh[n,:] + sWs[b,n] + cov[bs]*wc[n] + ab[n]) * av[n]
__global__ __launch_bounds__(256)
void feat_mfma_kernel(const __bf16* __restrict__ enc, const __bf16* __restrict__ Wh,
                      const float* __restrict__ sWs, const float* __restrict__ cov,
                      const float* __restrict__ wcv, const float* __restrict__ ab,
                      const float* __restrict__ av_, float* __restrict__ e_part)
{
  __shared__ __attribute__((aligned(16))) __bf16 As[BM * BK];
  __shared__ __attribute__((aligned(16))) __bf16 Bs[BN * BK];
  __shared__ float red[BM][2];
  const int tid  = threadIdx.x;
  const int lane = tid & 63, wid = tid >> 6;
  const int wr = wid >> 1, wcc = wid & 1;
  // bijective XCD-chunked swizzle (nwg=4096): each XCD gets contiguous swz range,
  // n-tile (y) cycles fastest so the 8 n-tiles of one enc tile run on the SAME XCD L2.
  const int bid = blockIdx.x;
  const int swz = (bid & 7) * 512 + (bid >> 3);
  const int bs0 = (swz >> 3) * BM;   // bs-tile
  const int n0  = (swz & 7) * BN;    // n-tile
  const int b   = bs0 / S_;

  f32x4 acc[4][4];
#pragma unroll
  for (int i = 0; i < 4; i++)
#pragma unroll
    for (int j = 0; j < 4; j++) acc[i][j] = (f32x4){0.f, 0.f, 0.f, 0.f};

  for (int k0 = 0; k0 < H_; k0 += BK) {
    // stage A,B tiles: linear LDS dest, inverse-swizzled per-lane global source
#pragma unroll
    for (int p = 0; p < 4; ++p) {
      int off = p * 4096 + tid * 16;          // dest byte offset
      int r = off >> 7, cb = off & 127;       // row, col-byte within row (128B rows)
      int scb = cb ^ ((r & 7) << 4);          // source col-byte (XOR swizzle)
      gload_lds16(enc + (size_t)(bs0 + r) * H_ + k0 + (scb >> 1), (char*)As + off);
      gload_lds16(Wh  + (size_t)(n0 + r) * H_ + k0 + (scb >> 1), (char*)Bs + off);
    }
    __syncthreads();  // drains vmcnt before barrier

    bf16x8 af[4][2], bf[4][2];
#pragma unroll
    for (int m = 0; m < 4; ++m) {
      int row = wr * 64 + m * 16 + (lane & 15);
      int swzb = (row & 7) << 4;
#pragma unroll
      for (int kk = 0; kk < 2; ++kk) {
        int kb = kk * 64 + ((lane >> 4) << 4);
        af[m][kk] = *(const bf16x8*)((const char*)As + row * 128 + (kb ^ swzb));
      }
    }
#pragma unroll
    for (int n = 0; n < 4; ++n) {
      int row = wcc * 64 + n * 16 + (lane & 15);
      int swzb = (row & 7) << 4;
#pragma unroll
      for (int kk = 0; kk < 2; ++kk) {
        int kb = kk * 64 + ((lane >> 4) << 4);
        bf[n][kk] = *(const bf16x8*)((const char*)Bs + row * 128 + (kb ^ swzb));
      }
    }
#pragma unroll
    for (int m = 0; m < 4; ++m)
#pragma unroll
      for (int n = 0; n < 4; ++n)
#pragma unroll
        for (int kk = 0; kk < 2; ++kk)
          acc[m][n] = __builtin_amdgcn_mfma_f32_16x16x32_bf16(af[m][kk], bf[n][kk], acc[m][n], 0, 0, 0);
    __syncthreads();
  }

  // epilogue: +sWs +cov*wc +b, tanh, *av, reduce over the 128 columns of this tile
  float rowsum[4][4];
#pragma unroll
  for (int m = 0; m < 4; m++)
#pragma unroll
    for (int j = 0; j < 4; j++) rowsum[m][j] = 0.f;

#pragma unroll
  for (int m = 0; m < 4; ++m) {
#pragma unroll
    for (int n = 0; n < 4; ++n) {
      int col_g = n0 + wcc * 64 + n * 16 + (lane & 15);
      float sw = sWs[(size_t)b * H_ + col_g];
      float wc_n = wcv[col_g], ab_n = ab[col_g], av_n = av_[col_g];
#pragma unroll
      for (int j = 0; j < 4; ++j) {
        int row_l = wr * 64 + m * 16 + ((lane >> 4) << 2) + j;
        float val = acc[m][n][j] + sw + cov[bs0 + row_l] * wc_n + ab_n;
        rowsum[m][j] += tanhf(val) * av_n;
      }
    }
  }
#pragma unroll
  for (int m = 0; m < 4; ++m)
#pragma unroll
    for (int j = 0; j < 4; ++j) {
      float v = rowsum[m][j];
      v += __shfl_xor(v, 1);
      v += __shfl_xor(v, 2);
      v += __shfl_xor(v, 4);
      v += __shfl_xor(v, 8);
      rowsum[m][j] = v;
    }
  if ((lane & 15) == 0) {
#pragma unroll
    for (int m = 0; m < 4; ++m)
#pragma unroll
      for (int j = 0; j < 4; ++j)
        red[wr * 64 + m * 16 + ((lane >> 4) << 2) + j][wcc] = rowsum[m][j];
  }
  __syncthreads();
  if (tid < BM)
    e_part[(size_t)(swz & 7) * (B_ * S_) + bs0 + tid] = red[tid][0] + red[tid][1];
}

// ------------- MFMA logits GEMM: out0[b, v] = out1[b,:]·e2v2_w[v,:] + bias[v] -------------
__global__ __launch_bounds__(256)
void logits_mfma_kernel(const __bf16* __restrict__ A, const float* __restrict__ W,
                        const float* __restrict__ bias, float* __restrict__ out0)
{
  __shared__ __attribute__((aligned(16))) __bf16 As[BM * BK];
  __shared__ __attribute__((aligned(16))) __bf16 Bs[BN * BK];
  const int tid  = threadIdx.x;
  const int lane = tid & 63, wid = tid >> 6;
  const int wr = wid >> 1, wcc = wid & 1;
  const int n0 = blockIdx.x * BN;

  f32x4 acc[4][4];
#pragma unroll
  for (int i = 0; i < 4; i++)
#pragma unroll
    for (int j = 0; j < 4; j++) acc[i][j] = (f32x4){0.f, 0.f, 0.f, 0.f};

  for (int k0 = 0; k0 < F_; k0 += BK) {
    // A: async global->LDS (bf16, 128x64)
#pragma unroll
    for (int p = 0; p < 4; ++p) {
      int off = p * 4096 + tid * 16;
      int r = off >> 7, cb = off & 127;
      int scb = cb ^ ((r & 7) << 4);
      gload_lds16(A + (size_t)r * F_ + k0 + (scb >> 1), (char*)As + off);
    }
    // B: fp32 load + convert + swizzled ds_write (W rows clamped at V-1 for the tail tile)
#pragma unroll
    for (int p = 0; p < 8; ++p) {
      int idx = p * 1024 + tid * 4;           // element index in 128x64 tile
      int r = idx >> 6, c = idx & 63;
      int row_g = n0 + r; if (row_g >= V_) row_g = V_ - 1;
      float4 f = *(const float4*)(W + (size_t)row_g * F_ + k0 + c);
      union { __bf16 h[4]; uint2 u; } t;
      t.h[0] = (__bf16)f.x; t.h[1] = (__bf16)f.y; t.h[2] = (__bf16)f.z; t.h[3] = (__bf16)f.w;
      int cb = c * 2;
      *(uint2*)((char*)Bs + r * 128 + (cb ^ ((r & 7) << 4))) = t.u;
    }
    __syncthreads();

    bf16x8 af[4][2], bf[4][2];
#pragma unroll
    for (int m = 0; m < 4; ++m) {
      int row = wr * 64 + m * 16 + (lane & 15);
      int swz = (row & 7) << 4;
#pragma unroll
      for (int kk = 0; kk < 2; ++kk) {
        int kb = kk * 64 + ((lane >> 4) << 4);
        af[m][kk] = *(const bf16x8*)((const char*)As + row * 128 + (kb ^ swz));
      }
    }
#pragma unroll
    for (int n = 0; n < 4; ++n) {
      int row = wcc * 64 + n * 16 + (lane & 15);
      int swz = (row & 7) << 4;
#pragma unroll
      for (int kk = 0; kk < 2; ++kk) {
        int kb = kk * 64 + ((lane >> 4) << 4);
        bf[n][kk] = *(const bf16x8*)((const char*)Bs + row * 128 + (kb ^ swz));
      }
    }
#pragma unroll
    for (int m = 0; m < 4; ++m)
#pragma unroll
      for (int n = 0; n < 4; ++n)
#pragma unroll
        for (int kk = 0; kk < 2; ++kk)
          acc[m][n] = __builtin_amdgcn_mfma_f32_16x16x32_bf16(af[m][kk], bf[n][kk], acc[m][n], 0, 0, 0);
    __syncthreads();
  }

#pragma unroll
  for (int m = 0; m < 4; ++m) {
#pragma unroll
    for (int n = 0; n < 4; ++n) {
      int col_g = n0 + wcc * 64 + n * 16 + (lane & 15);
      if (col_g >= V_) continue;
      float bv = bias[col_g];
#pragma unroll
      for (int j = 0; j < 4; ++j) {
        int row = wr * 64 + m * 16 + ((lane >> 4) << 2) + j;  // row < 128 == B_
        out0[(size_t)row * EV_ + col_g] = acc[m][n][j] + bv;
      }
    }
  }
}

// ---------------- softmax over S with mask + renorm; writes a and coverage ----------------
__global__ __launch_bounds__(512)
void softmax_a_kernel(const float* __restrict__ e_part, const float* __restrict__ mask,
                      const float* __restrict__ cov, float* __restrict__ a_ws,
                      float* __restrict__ out_a, float* __restrict__ out_cov)
{
  const int b = blockIdx.x;
  const int s = threadIdx.x;  // 512
  __shared__ float red[512];
  float e = 0.f;
  for (int kt = 0; kt < 8; ++kt) e += e_part[(size_t)kt * (B_ * S_) + b * S_ + s];
  red[s] = e;
  __syncthreads();
  for (int st = 256; st > 0; st >>= 1) {
    if (s < st) red[s] = fmaxf(red[s], red[s + st]);
    __syncthreads();
  }
  float mx = red[0];
  __syncthreads();
  float ex = expf(e - mx) * mask[b * S_ + s];
  red[s] = ex;
  __syncthreads();
  for (int st = 256; st > 0; st >>= 1) {
    if (s < st) red[s] += red[s + st];
    __syncthreads();
  }
  float a = ex / red[0];
  a_ws[b * S_ + s] = a;
  out_a[b * S_ + s] = a;
  out_cov[b * S_ + s] = cov[b * S_ + s] + a;
}

// ---------------- context[b,h] = sum_s a[b,s] * enc[b,s,h] ----------------
__global__ __launch_bounds__(256)
void context_kernel(const float* __restrict__ a_ws, const float* __restrict__ enc,
                    float* __restrict__ context)
{
  const int b = blockIdx.y;
  const int h = blockIdx.x * 256 + threadIdx.x;
  __shared__ float al[S_];
  for (int i = threadIdx.x; i < S_; i += 256) al[i] = a_ws[b * S_ + i];
  __syncthreads();
  float acc = 0.f;
  const float* ep = enc + (size_t)b * S_ * H_ + h;
  for (int s = 0; s < S_; ++s) acc = fmaf(al[s], ep[(size_t)s * H_], acc);
  context[b * H_ + h] = acc;
}

__global__ void xcat_kernel(const float* __restrict__ hidden, const float* __restrict__ context,
                            float* __restrict__ x_cat)
{
  int b = blockIdx.x;
  for (int j = threadIdx.x; j < 2 * H_; j += blockDim.x)
    x_cat[b * 2 * H_ + j] = (j < H_) ? hidden[b * H_ + j] : context[b * H_ + j - H_];
}

__global__ void gather_emb_kernel(const int* __restrict__ input, const float* __restrict__ emb,
                                  float* __restrict__ emb_x)
{
  int b = blockIdx.x;
  int row = input[b];
  for (int f = threadIdx.x; f < F_; f += 256)
    emb_x[b * F_ + f] = emb[(size_t)row * F_ + f];
}

__global__ void gru_kernel(const float* __restrict__ gi, const float* __restrict__ gh,
                           const float* __restrict__ h_att, float* __restrict__ h_new_ws,
                           float* __restrict__ out_h)
{
  int idx = blockIdx.x * 256 + threadIdx.x;  // B*H
  int b = idx / H_, h = idx % H_;
  float ir = gi[(size_t)b * 3 * H_ + h],           hr = gh[(size_t)b * 3 * H_ + h];
  float iz = gi[(size_t)b * 3 * H_ + H_ + h],      hz = gh[(size_t)b * 3 * H_ + H_ + h];
  float in_ = gi[(size_t)b * 3 * H_ + 2 * H_ + h], hn = gh[(size_t)b * 3 * H_ + 2 * H_ + h];
  float r = 1.f / (1.f + expf(-(ir + hr)));
  float z = 1.f / (1.f + expf(-(iz + hz)));
  float n = tanhf(in_ + r * hn);
  float ha = h_att[(size_t)b * H_ + h];
  float hv = (1.f - z) * n + z * ha;
  h_new_ws[idx] = hv;
  out_h[idx] = hv;
}

__global__ __launch_bounds__(256)
void pgen_kernel(const float* __restrict__ context, const float* __restrict__ h_new,
                 const float* __restrict__ emb_x, const float* __restrict__ wgen_w,
                 const float* __restrict__ wgen_b, float* __restrict__ pgen)
{
  int b = blockIdx.x;
  float acc = 0.f;
  for (int j = threadIdx.x; j < H_; j += 256) acc = fmaf(context[b * H_ + j], wgen_w[j], acc);
  for (int j = threadIdx.x; j < H_; j += 256) acc = fmaf(h_new[b * H_ + j], wgen_w[H_ + j], acc);
  for (int j = threadIdx.x; j < F_; j += 256) acc = fmaf(emb_x[b * F_ + j], wgen_w[2 * H_ + j], acc);
  __shared__ float red[256];
  red[threadIdx.x] = acc;
  __syncthreads();
  for (int st = 128; st > 0; st >>= 1) {
    if (threadIdx.x < st) red[threadIdx.x] += red[threadIdx.x + st];
    __syncthreads();
  }
  if (threadIdx.x == 0) {
    float p = 1.f / (1.f + expf(-(red[0] + wgen_b[0])));
    p = fminf(fmaxf(p, 0.001f), 0.999f);
    pgen[b] = p;
  }
}

__global__ __launch_bounds__(512)
void vstats_kernel(const float* __restrict__ logits, float* __restrict__ vmax,
                   float* __restrict__ vsum)
{
  int b = blockIdx.x;
  const float* row = logits + (size_t)b * EV_;
  __shared__ float red[512];
  float m = -1e30f;
  for (int v = threadIdx.x; v < V_; v += 512) m = fmaxf(m, row[v]);
  red[threadIdx.x] = m;
  __syncthreads();
  for (int st = 256; st > 0; st >>= 1) {
    if (threadIdx.x < st) red[threadIdx.x] = fmaxf(red[threadIdx.x], red[threadIdx.x + st]);
    __syncthreads();
  }
  m = red[0];
  __syncthreads();
  float ssum = 0.f;
  for (int v = threadIdx.x; v < V_; v += 512) ssum += expf(row[v] - m);
  red[threadIdx.x] = ssum;
  __syncthreads();
  for (int st = 256; st > 0; st >>= 1) {
    if (threadIdx.x < st) red[threadIdx.x] += red[threadIdx.x + st];
    __syncthreads();
  }
  if (threadIdx.x == 0) { vmax[b] = m; vsum[b] = red[0]; }
}

__global__ void final_kernel(float* __restrict__ out0, const float* __restrict__ vmax,
                             const float* __restrict__ vsum, const float* __restrict__ pgen)
{
  int b = blockIdx.y;
  int v = blockIdx.x * 256 + threadIdx.x;
  if (v >= EV_) return;
  float* row = out0 + (size_t)b * EV_;
  if (v < V_) row[v] = pgen[b] * expf(row[v] - vmax[b]) / vsum[b];
  else row[v] = 0.f;
}

__global__ void scatter_kernel(const int* __restrict__ ref2tgt, const float* __restrict__ a_ws,
                               const float* __restrict__ pgen, float* __restrict__ out0)
{
  int b = blockIdx.x;
  int s = threadIdx.x;  // 512
  float w = (1.f - pgen[b]) * a_ws[b * S_ + s];
  int t = ref2tgt[b * S_ + s];
  atomicAdd(&out0[(size_t)b * EV_ + t], w);
}

extern "C" void kernel_launch(void* const* d_in, const int* in_sizes, int n_in,
                              void* d_out, int out_size, void* d_ws, size_t ws_size,
                              hipStream_t stream)
{
  const int*   input   = (const int*)d_in[0];
  const float* hidden  = (const float*)d_in[1];
  const float* enc     = (const float*)d_in[2];
  const float* mask    = (const float*)d_in[3];
  const float* cov     = (const float*)d_in[5];
  const int*   ref2tgt = (const int*)d_in[6];
  const float* emb     = (const float*)d_in[7];
  const float* W_ih    = (const float*)d_in[8];
  const float* W_hh    = (const float*)d_in[9];
  const float* b_ih    = (const float*)d_in[10];
  const float* b_hh    = (const float*)d_in[11];
  const float* e2v1_w  = (const float*)d_in[12];
  const float* e2v1_b  = (const float*)d_in[13];
  const float* e2v2_w  = (const float*)d_in[14];
  const float* e2v2_b  = (const float*)d_in[15];
  const float* fc_w    = (const float*)d_in[16];
  const float* fc_b    = (const float*)d_in[17];
  const float* wgen_w  = (const float*)d_in[18];
  const float* wgen_b  = (const float*)d_in[19];
  const float* att_Wh  = (const float*)d_in[20];
  const float* att_Ws  = (const float*)d_in[21];
  const float* att_wc  = (const float*)d_in[22];
  const float* att_b   = (const float*)d_in[23];
  const float* att_v   = (const float*)d_in[24];

  char* w = (char*)d_ws;
  __bf16* enc_h  = (__bf16*)w;  w += (size_t)B_ * S_ * H_ * 2;   // 134.2 MB
  __bf16* Wh_h   = (__bf16*)w;  w += (size_t)H_ * H_ * 2;        // 2 MB
  __bf16* out1_h = (__bf16*)w;  w += (size_t)B_ * F_ * 2;        // 128 KB
  float* sWs     = (float*)w;   w += (size_t)B_ * H_ * 4;
  float* e_part  = (float*)w;   w += (size_t)8 * B_ * S_ * 4;
  float* a_ws    = (float*)w;   w += (size_t)B_ * S_ * 4;
  float* context = (float*)w;   w += (size_t)B_ * H_ * 4;
  float* x_cat   = (float*)w;   w += (size_t)B_ * 2 * H_ * 4;
  float* h_att   = (float*)w;   w += (size_t)B_ * H_ * 4;
  float* emb_x   = (float*)w;   w += (size_t)B_ * F_ * 4;
  float* gi      = (float*)w;   w += (size_t)B_ * 3 * H_ * 4;
  float* gh      = (float*)w;   w += (size_t)B_ * 3 * H_ * 4;
  float* h_new   = (float*)w;   w += (size_t)B_ * H_ * 4;
  float* out1    = (float*)w;   w += (size_t)B_ * F_ * 4;
  float* pgen    = (float*)w;   w += 128 * 4;
  float* vmax    = (float*)w;   w += 128 * 4;
  float* vsum    = (float*)w;   w += 128 * 4;
  float* partial = (float*)w;   w += (size_t)16 * 128 * 3072 * 4;  // 12 MB max (reused)

  float* out0    = (float*)d_out;                 // final [B, EV]
  float* out_h   = out0 + (size_t)B_ * EV_;       // h_new [1,B,H]
  float* out_cov = out_h + (size_t)B_ * H_;       // coverage_new [B,S]
  float* out_a   = out_cov + (size_t)B_ * S_;     // a [B,S]

  // bf16 casts (enc is the big one: 134 MB -> fits L3 for the n-tile re-reads)
  f32_to_bf16_kernel<<<4096, 256, 0, stream>>>(enc, enc_h, B_ * S_ * H_);
  f32_to_bf16_kernel<<<512, 256, 0, stream>>>(att_Wh, Wh_h, H_ * H_);

  gather_emb_kernel<<<B_, 256, 0, stream>>>(input, emb, emb_x);

  // sWs = s @ att_Ws^T   (N=1024, K=1024, KS=64 -> grid 32x16, P=16)
  gemm_splitk<<<dim3(32, 16), 256, 0, stream>>>(hidden, att_Ws, partial, H_, H_, 64);
  reduce_partial<<<512, 256, 0, stream>>>(partial, nullptr, sWs, H_, 16);

  feat_mfma_kernel<<<dim3(4096), 256, 0, stream>>>(
      enc_h, Wh_h, sWs, cov, att_wc, att_b, att_v, e_part);
  softmax_a_kernel<<<B_, 512, 0, stream>>>(e_part, mask, cov, a_ws, out_a, out_cov);
  context_kernel<<<dim3(H_ / 256, B_), 256, 0, stream>>>(a_ws, enc, context);
  xcat_kernel<<<B_, 256, 0, stream>>>(hidden, context, x_cat);

  // h_att = [s, context] @ fc_w^T + fc_b   (N=1024, K=2048, KS=128 -> grid 32x16, P=16)
  gemm_splitk<<<dim3(32, 16), 256, 0, stream>>>(x_cat, fc_w, partial, H_, 2 * H_, 128);
  reduce_partial<<<512, 256, 0, stream>>>(partial, fc_b, h_att, H_, 16);

  // gi = emb_x @ W_ih^T + b_ih   (N=3072, K=512, KS=64 -> grid 96x8, P=8)
  gemm_splitk<<<dim3(96, 8), 256, 0, stream>>>(emb_x, W_ih, partial, 3 * H_, F_, 64);
  reduce_partial<<<1536, 256, 0, stream>>>(partial, b_ih, gi, 3 * H_, 8);

  // gh = h_att @ W_hh^T + b_hh   (N=3072, K=1024, KS=128 -> grid 96x8, P=8)
  gemm_splitk<<<dim3(96, 8), 256, 0, stream>>>(h_att, W_hh, partial, 3 * H_, H_, 128);
  reduce_partial<<<1536, 256, 0, stream>>>(partial, b_hh, gh, 3 * H_, 8);

  gru_kernel<<<(B_ * H_) / 256, 256, 0, stream>>>(gi, gh, h_att, h_new, out_h);

  // out1 = h_new @ e2v1_w^T + e2v1_b   (N=512, K=1024, KS=64 -> grid 16x16, P=16)
  gemm_splitk<<<dim3(16, 16), 256, 0, stream>>>(h_new, e2v1_w, partial, F_, H_, 64);
  reduce_partial<<<256, 256, 0, stream>>>(partial, e2v1_b, out1, F_, 16);

  f32_to_bf16_kernel<<<32, 256, 0, stream>>>(out1, out1_h, B_ * F_);
  logits_mfma_kernel<<<dim3((V_ + BN - 1) / BN), 256, 0, stream>>>(out1_h, e2v2_w, e2v2_b, out0);

  pgen_kernel<<<B_, 256, 0, stream>>>(context, h_new, emb_x, wgen_w, wgen_b, pgen);
  vstats_kernel<<<B_, 512, 0, stream>>>(out0, vmax, vsum);
  final_kernel<<<dim3((EV_ + 255) / 256, B_), 256, 0, stream>>>(out0, vmax, vsum, pgen);
  scatter_kernel<<<B_, 512, 0, stream>>>(ref2tgt, a_ws, pgen, out0);
}

// Round 4
// 524.804 us; speedup vs baseline: 12.3448x; 1.0913x over previous
//
#include <hip/hip_runtime.h>
#include <math.h>

#define B_   128
#define S_   512
#define H_   1024
#define F_   512
#define V_   50000
#define OOV_ 50
#define EV_  (V_ + OOV_)   // 50050

#define BM 128
#define BN 128
#define BK 64

typedef __attribute__((ext_vector_type(8))) __bf16 bf16x8;
typedef __attribute__((ext_vector_type(4))) __bf16 bf16x4;
typedef __attribute__((ext_vector_type(4))) float  f32x4;

__device__ __forceinline__ void gload_lds16(const void* g, void* lds) {
  __builtin_amdgcn_global_load_lds(
      (const __attribute__((address_space(1))) unsigned int*)g,
      (__attribute__((address_space(3))) unsigned int*)lds, 16, 0, 0);
}

__device__ __forceinline__ float fast_tanh(float x) {
  float v = fminf(fmaxf(x, -15.f), 15.f);
  float t = __expf(2.f * v);
  return 1.f - 2.f / (t + 1.f);
}

// ---------------- combined fp32 -> bf16 cast: enc then Wh ----------------
__global__ __launch_bounds__(256)
void cast_both_kernel(const float* __restrict__ enc, __bf16* __restrict__ enc_h,
                      const float* __restrict__ wh, __bf16* __restrict__ wh_h)
{
  const size_t n_enc = (size_t)B_ * S_ * H_;
  const size_t n_tot = n_enc + (size_t)H_ * H_;
  for (size_t i = ((size_t)blockIdx.x * 256 + threadIdx.x) * 8; i < n_tot;
       i += (size_t)gridDim.x * 256 * 8) {
    const float* in; __bf16* out; size_t j;
    if (i < n_enc) { in = enc; out = enc_h; j = i; }
    else           { in = wh;  out = wh_h;  j = i - n_enc; }
    float4 a = *(const float4*)(in + j);
    float4 b = *(const float4*)(in + j + 4);
    bf16x8 o;
    o[0] = (__bf16)a.x; o[1] = (__bf16)a.y; o[2] = (__bf16)a.z; o[3] = (__bf16)a.w;
    o[4] = (__bf16)b.x; o[5] = (__bf16)b.y; o[6] = (__bf16)b.z; o[7] = (__bf16)b.w;
    *(bf16x8*)(out + j) = o;
  }
}

// ---------------- split-K fp32 GEMM core (macro-free triplet) ----------------
// C_partial[p][m][n] = A[128, K-slice p] @ W[N, K-slice p]^T, 128x32x64 steps.
__global__ __launch_bounds__(256)
void gemm_splitk(const float* __restrict__ A, const float* __restrict__ W,
                 float* __restrict__ partial, int N, int K, int KS)
{
  __shared__ float As[128 * 68];
  __shared__ float Ws[32 * 68];
  const int tid = threadIdx.x;
  const int n0 = blockIdx.x * 32;
  const int p  = blockIdx.y;
  const int tx = tid & 7, ty = tid >> 3;
  const int lr = tid >> 4, lc4 = (tid & 15) * 4;
  float acc[4][4] = {};
  const int kend = p * KS + KS;
  for (int k0 = p * KS; k0 < kend; k0 += 64) {
#pragma unroll
    for (int pp = 0; pp < 8; ++pp)
      *(float4*)(As + (pp * 16 + lr) * 68 + lc4) =
          *(const float4*)(A + (size_t)(pp * 16 + lr) * K + k0 + lc4);
#pragma unroll
    for (int pp = 0; pp < 2; ++pp)
      *(float4*)(Ws + (pp * 16 + lr) * 68 + lc4) =
          *(const float4*)(W + (size_t)(n0 + pp * 16 + lr) * K + k0 + lc4);
    __syncthreads();
#pragma unroll
    for (int kk = 0; kk < 16; ++kk) {
      float4 av[4], wv[4];
#pragma unroll
      for (int i = 0; i < 4; i++) av[i] = *(const float4*)(As + (ty * 4 + i) * 68 + kk * 4);
#pragma unroll
      for (int j = 0; j < 4; j++) wv[j] = *(const float4*)(Ws + (tx * 4 + j) * 68 + kk * 4);
#pragma unroll
      for (int i = 0; i < 4; i++)
#pragma unroll
        for (int j = 0; j < 4; j++) {
          acc[i][j] = fmaf(av[i].x, wv[j].x, acc[i][j]);
          acc[i][j] = fmaf(av[i].y, wv[j].y, acc[i][j]);
          acc[i][j] = fmaf(av[i].z, wv[j].z, acc[i][j]);
          acc[i][j] = fmaf(av[i].w, wv[j].w, acc[i][j]);
        }
    }
    __syncthreads();
  }
#pragma unroll
  for (int i = 0; i < 4; i++)
#pragma unroll
    for (int j = 0; j < 4; j++)
      partial[((size_t)p * 128 + ty * 4 + i) * N + n0 + tx * 4 + j] = acc[i][j];
}

// variant: A = concat(A1[128,1024], A2[128,1024]) along K (KS=128 keeps p in one half)
__global__ __launch_bounds__(256)
void gemm_splitk_cat(const float* __restrict__ A1, const float* __restrict__ A2,
                     const float* __restrict__ W, float* __restrict__ partial,
                     int N, int K, int KS)
{
  __shared__ float As[128 * 68];
  __shared__ float Ws[32 * 68];
  const int tid = threadIdx.x;
  const int n0 = blockIdx.x * 32;
  const int p  = blockIdx.y;
  const int tx = tid & 7, ty = tid >> 3;
  const int lr = tid >> 4, lc4 = (tid & 15) * 4;
  const float* A = (p * KS < 1024) ? A1 : A2;
  const int kbase = (p * KS < 1024) ? 0 : 1024;
  float acc[4][4] = {};
  const int kend = p * KS + KS;
  for (int k0 = p * KS; k0 < kend; k0 += 64) {
#pragma unroll
    for (int pp = 0; pp < 8; ++pp)
      *(float4*)(As + (pp * 16 + lr) * 68 + lc4) =
          *(const float4*)(A + (size_t)(pp * 16 + lr) * 1024 + (k0 - kbase) + lc4);
#pragma unroll
    for (int pp = 0; pp < 2; ++pp)
      *(float4*)(Ws + (pp * 16 + lr) * 68 + lc4) =
          *(const float4*)(W + (size_t)(n0 + pp * 16 + lr) * K + k0 + lc4);
    __syncthreads();
#pragma unroll
    for (int kk = 0; kk < 16; ++kk) {
      float4 av[4], wv[4];
#pragma unroll
      for (int i = 0; i < 4; i++) av[i] = *(const float4*)(As + (ty * 4 + i) * 68 + kk * 4);
#pragma unroll
      for (int j = 0; j < 4; j++) wv[j] = *(const float4*)(Ws + (tx * 4 + j) * 68 + kk * 4);
#pragma unroll
      for (int i = 0; i < 4; i++)
#pragma unroll
        for (int j = 0; j < 4; j++) {
          acc[i][j] = fmaf(av[i].x, wv[j].x, acc[i][j]);
          acc[i][j] = fmaf(av[i].y, wv[j].y, acc[i][j]);
          acc[i][j] = fmaf(av[i].z, wv[j].z, acc[i][j]);
          acc[i][j] = fmaf(av[i].w, wv[j].w, acc[i][j]);
        }
    }
    __syncthreads();
  }
#pragma unroll
  for (int i = 0; i < 4; i++)
#pragma unroll
    for (int j = 0; j < 4; j++)
      partial[((size_t)p * 128 + ty * 4 + i) * N + n0 + tx * 4 + j] = acc[i][j];
}

// variant: A rows gathered from emb via input[] (kills gather kernel + emb_x buffer)
__global__ __launch_bounds__(256)
void gemm_splitk_gather(const int* __restrict__ input, const float* __restrict__ emb,
                        const float* __restrict__ W, float* __restrict__ partial,
                        int N, int K, int KS)
{
  __shared__ float As[128 * 68];
  __shared__ float Ws[32 * 68];
  const int tid = threadIdx.x;
  const int n0 = blockIdx.x * 32;
  const int p  = blockIdx.y;
  const int tx = tid & 7, ty = tid >> 3;
  const int lr = tid >> 4, lc4 = (tid & 15) * 4;
  float acc[4][4] = {};
  const int kend = p * KS + KS;
  for (int k0 = p * KS; k0 < kend; k0 += 64) {
#pragma unroll
    for (int pp = 0; pp < 8; ++pp) {
      int row = input[pp * 16 + lr];
      *(float4*)(As + (pp * 16 + lr) * 68 + lc4) =
          *(const float4*)(emb + (size_t)row * K + k0 + lc4);
    }
#pragma unroll
    for (int pp = 0; pp < 2; ++pp)
      *(float4*)(Ws + (pp * 16 + lr) * 68 + lc4) =
          *(const float4*)(W + (size_t)(n0 + pp * 16 + lr) * K + k0 + lc4);
    __syncthreads();
#pragma unroll
    for (int kk = 0; kk < 16; ++kk) {
      float4 av[4], wv[4];
#pragma unroll
      for (int i = 0; i < 4; i++) av[i] = *(const float4*)(As + (ty * 4 + i) * 68 + kk * 4);
#pragma unroll
      for (int j = 0; j < 4; j++) wv[j] = *(const float4*)(Ws + (tx * 4 + j) * 68 + kk * 4);
#pragma unroll
      for (int i = 0; i < 4; i++)
#pragma unroll
        for (int j = 0; j < 4; j++) {
          acc[i][j] = fmaf(av[i].x, wv[j].x, acc[i][j]);
          acc[i][j] = fmaf(av[i].y, wv[j].y, acc[i][j]);
          acc[i][j] = fmaf(av[i].z, wv[j].z, acc[i][j]);
          acc[i][j] = fmaf(av[i].w, wv[j].w, acc[i][j]);
        }
    }
    __syncthreads();
  }
#pragma unroll
  for (int i = 0; i < 4; i++)
#pragma unroll
    for (int j = 0; j < 4; j++)
      partial[((size_t)p * 128 + ty * 4 + i) * N + n0 + tx * 4 + j] = acc[i][j];
}

__global__ __launch_bounds__(256)
void reduce_partial(const float* __restrict__ partial, const float* __restrict__ bias,
                    float* __restrict__ C, int N, int P)
{
  int idx = blockIdx.x * 256 + threadIdx.x;
  int n = idx % N;
  float s = bias ? bias[n] : 0.f;
  for (int p = 0; p < P; ++p) s += partial[(size_t)p * 128 * N + idx];
  C[idx] = s;
}

__global__ __launch_bounds__(256)
void reduce_partial_bf16(const float* __restrict__ partial, const float* __restrict__ bias,
                         __bf16* __restrict__ C, int N, int P)
{
  int idx = blockIdx.x * 256 + threadIdx.x;
  int n = idx % N;
  float s = bias ? bias[n] : 0.f;
  for (int p = 0; p < P; ++p) s += partial[(size_t)p * 128 * N + idx];
  C[idx] = (__bf16)s;
}

// ------------- MFMA attention feature GEMM + tanh + dot(v) reduction -------------
__global__ __launch_bounds__(256)
void feat_mfma_kernel(const __bf16* __restrict__ enc, const __bf16* __restrict__ Wh,
                      const float* __restrict__ pSWS, const float* __restrict__ cov,
                      const float* __restrict__ wcv, const float* __restrict__ ab,
                      const float* __restrict__ av_, float* __restrict__ e_part)
{
  __shared__ __attribute__((aligned(16))) __bf16 As[BM * BK];
  __shared__ __attribute__((aligned(16))) __bf16 Bs[BN * BK];
  __shared__ float red[BM][2];
  const int tid  = threadIdx.x;
  const int lane = tid & 63, wid = tid >> 6;
  const int wr = wid >> 1, wcc = wid & 1;
  const int bid = blockIdx.x;
  const int swz = (bid & 7) * 512 + (bid >> 3);   // bijective XCD swizzle (nwg=4096)
  const int bs0 = (swz >> 3) * BM;
  const int n0  = (swz & 7) * BN;
  const int b   = bs0 / S_;

  f32x4 acc[4][4];
#pragma unroll
  for (int i = 0; i < 4; i++)
#pragma unroll
    for (int j = 0; j < 4; j++) acc[i][j] = (f32x4){0.f, 0.f, 0.f, 0.f};

  for (int k0 = 0; k0 < H_; k0 += BK) {
#pragma unroll
    for (int p = 0; p < 4; ++p) {
      int off = p * 4096 + tid * 16;
      int r = off >> 7, cb = off & 127;
      int scb = cb ^ ((r & 7) << 4);
      gload_lds16(enc + (size_t)(bs0 + r) * H_ + k0 + (scb >> 1), (char*)As + off);
      gload_lds16(Wh  + (size_t)(n0 + r) * H_ + k0 + (scb >> 1), (char*)Bs + off);
    }
    __syncthreads();

    bf16x8 af[4][2], bfv[4][2];
#pragma unroll
    for (int m = 0; m < 4; ++m) {
      int row = wr * 64 + m * 16 + (lane & 15);
      int swzb = (row & 7) << 4;
#pragma unroll
      for (int kk = 0; kk < 2; ++kk) {
        int kb = kk * 64 + ((lane >> 4) << 4);
        af[m][kk] = *(const bf16x8*)((const char*)As + row * 128 + (kb ^ swzb));
      }
    }
#pragma unroll
    for (int n = 0; n < 4; ++n) {
      int row = wcc * 64 + n * 16 + (lane & 15);
      int swzb = (row & 7) << 4;
#pragma unroll
      for (int kk = 0; kk < 2; ++kk) {
        int kb = kk * 64 + ((lane >> 4) << 4);
        bfv[n][kk] = *(const bf16x8*)((const char*)Bs + row * 128 + (kb ^ swzb));
      }
    }
#pragma unroll
    for (int m = 0; m < 4; ++m)
#pragma unroll
      for (int n = 0; n < 4; ++n)
#pragma unroll
        for (int kk = 0; kk < 2; ++kk)
          acc[m][n] = __builtin_amdgcn_mfma_f32_16x16x32_bf16(af[m][kk], bfv[n][kk], acc[m][n], 0, 0, 0);
    __syncthreads();
  }

  // epilogue: sWs (16 split-K partials, L2-hot) + cov*wc + b, fast-tanh, *av, row-reduce
  float rowsum[4][4];
#pragma unroll
  for (int m = 0; m < 4; m++)
#pragma unroll
    for (int j = 0; j < 4; j++) rowsum[m][j] = 0.f;

#pragma unroll
  for (int n = 0; n < 4; ++n) {
    int col_g = n0 + wcc * 64 + n * 16 + (lane & 15);
    float sw = 0.f;
#pragma unroll
    for (int p = 0; p < 16; ++p) sw += pSWS[((size_t)p * 128 + b) * H_ + col_g];
    float wc_n = wcv[col_g], ab_n = ab[col_g], av_n = av_[col_g];
#pragma unroll
    for (int m = 0; m < 4; ++m) {
#pragma unroll
      for (int j = 0; j < 4; ++j) {
        int row_l = wr * 64 + m * 16 + ((lane >> 4) << 2) + j;
        float val = acc[m][n][j] + sw + cov[bs0 + row_l] * wc_n + ab_n;
        rowsum[m][j] += fast_tanh(val) * av_n;
      }
    }
  }
#pragma unroll
  for (int m = 0; m < 4; ++m)
#pragma unroll
    for (int j = 0; j < 4; ++j) {
      float v = rowsum[m][j];
      v += __shfl_xor(v, 1);
      v += __shfl_xor(v, 2);
      v += __shfl_xor(v, 4);
      v += __shfl_xor(v, 8);
      rowsum[m][j] = v;
    }
  if ((lane & 15) == 0) {
#pragma unroll
    for (int m = 0; m < 4; ++m)
#pragma unroll
      for (int j = 0; j < 4; ++j)
        red[wr * 64 + m * 16 + ((lane >> 4) << 2) + j][wcc] = rowsum[m][j];
  }
  __syncthreads();
  if (tid < BM)
    e_part[(size_t)(swz & 7) * (B_ * S_) + bs0 + tid] = red[tid][0] + red[tid][1];
}

// ------------- MFMA logits GEMM -------------
__global__ __launch_bounds__(256)
void logits_mfma_kernel(const __bf16* __restrict__ A, const float* __restrict__ W,
                        const float* __restrict__ bias, float* __restrict__ out0)
{
  __shared__ __attribute__((aligned(16))) __bf16 As[BM * BK];
  __shared__ __attribute__((aligned(16))) __bf16 Bs[BN * BK];
  const int tid  = threadIdx.x;
  const int lane = tid & 63, wid = tid >> 6;
  const int wr = wid >> 1, wcc = wid & 1;
  const int n0 = blockIdx.x * BN;

  f32x4 acc[4][4];
#pragma unroll
  for (int i = 0; i < 4; i++)
#pragma unroll
    for (int j = 0; j < 4; j++) acc[i][j] = (f32x4){0.f, 0.f, 0.f, 0.f};

  for (int k0 = 0; k0 < F_; k0 += BK) {
#pragma unroll
    for (int p = 0; p < 4; ++p) {
      int off = p * 4096 + tid * 16;
      int r = off >> 7, cb = off & 127;
      int scb = cb ^ ((r & 7) << 4);
      gload_lds16(A + (size_t)r * F_ + k0 + (scb >> 1), (char*)As + off);
    }
#pragma unroll
    for (int p = 0; p < 8; ++p) {
      int idx = p * 1024 + tid * 4;
      int r = idx >> 6, c = idx & 63;
      int row_g = n0 + r; if (row_g >= V_) row_g = V_ - 1;
      float4 f = *(const float4*)(W + (size_t)row_g * F_ + k0 + c);
      union { __bf16 h[4]; uint2 u; } t;
      t.h[0] = (__bf16)f.x; t.h[1] = (__bf16)f.y; t.h[2] = (__bf16)f.z; t.h[3] = (__bf16)f.w;
      int cb = c * 2;
      *(uint2*)((char*)Bs + r * 128 + (cb ^ ((r & 7) << 4))) = t.u;
    }
    __syncthreads();

    bf16x8 af[4][2], bfv[4][2];
#pragma unroll
    for (int m = 0; m < 4; ++m) {
      int row = wr * 64 + m * 16 + (lane & 15);
      int swz = (row & 7) << 4;
#pragma unroll
      for (int kk = 0; kk < 2; ++kk) {
        int kb = kk * 64 + ((lane >> 4) << 4);
        af[m][kk] = *(const bf16x8*)((const char*)As + row * 128 + (kb ^ swz));
      }
    }
#pragma unroll
    for (int n = 0; n < 4; ++n) {
      int row = wcc * 64 + n * 16 + (lane & 15);
      int swz = (row & 7) << 4;
#pragma unroll
      for (int kk = 0; kk < 2; ++kk) {
        int kb = kk * 64 + ((lane >> 4) << 4);
        bfv[n][kk] = *(const bf16x8*)((const char*)Bs + row * 128 + (kb ^ swz));
      }
    }
#pragma unroll
    for (int m = 0; m < 4; ++m)
#pragma unroll
      for (int n = 0; n < 4; ++n)
#pragma unroll
        for (int kk = 0; kk < 2; ++kk)
          acc[m][n] = __builtin_amdgcn_mfma_f32_16x16x32_bf16(af[m][kk], bfv[n][kk], acc[m][n], 0, 0, 0);
    __syncthreads();
  }

#pragma unroll
  for (int m = 0; m < 4; ++m) {
#pragma unroll
    for (int n = 0; n < 4; ++n) {
      int col_g = n0 + wcc * 64 + n * 16 + (lane & 15);
      if (col_g >= V_) continue;
      float bv = bias[col_g];
#pragma unroll
      for (int j = 0; j < 4; ++j) {
        int row = wr * 64 + m * 16 + ((lane >> 4) << 2) + j;
        out0[(size_t)row * EV_ + col_g] = acc[m][n][j] + bv;
      }
    }
  }
}

// ---------------- softmax over S + renorm + coverage ----------------
__global__ __launch_bounds__(512)
void softmax_a_kernel(const float* __restrict__ e_part, const float* __restrict__ mask,
                      const float* __restrict__ cov, float* __restrict__ a_ws,
                      float* __restrict__ out_a, float* __restrict__ out_cov)
{
  const int b = blockIdx.x;
  const int s = threadIdx.x;
  __shared__ float red[512];
  float e = 0.f;
  for (int kt = 0; kt < 8; ++kt) e += e_part[(size_t)kt * (B_ * S_) + b * S_ + s];
  red[s] = e;
  __syncthreads();
  for (int st = 256; st > 0; st >>= 1) {
    if (s < st) red[s] = fmaxf(red[s], red[s + st]);
    __syncthreads();
  }
  float mx = red[0];
  __syncthreads();
  float ex = expf(e - mx) * mask[b * S_ + s];
  red[s] = ex;
  __syncthreads();
  for (int st = 256; st > 0; st >>= 1) {
    if (s < st) red[s] += red[s + st];
    __syncthreads();
  }
  float a = ex / red[0];
  a_ws[b * S_ + s] = a;
  out_a[b * S_ + s] = a;
  out_cov[b * S_ + s] = cov[b * S_ + s] + a;
}

// ---------------- context[b,h] = sum_s a[b,s] * enc_h[b,s,h]  (bf16 enc) ----------------
__global__ __launch_bounds__(256)
void context_kernel(const float* __restrict__ a_ws, const __bf16* __restrict__ enc,
                    float* __restrict__ ctx)
{
  const int b = blockIdx.y, q = blockIdx.x;       // q = quarter of H (256 cols)
  const int lane = threadIdx.x & 63, w = threadIdx.x >> 6;
  const int h0 = q * 256 + lane * 4;
  __shared__ float al[S_];
  __shared__ float part[4][256];
  for (int i = threadIdx.x; i < S_; i += 256) al[i] = a_ws[b * S_ + i];
  __syncthreads();
  float acc0 = 0.f, acc1 = 0.f, acc2 = 0.f, acc3 = 0.f;
  const __bf16* ep = enc + (size_t)b * S_ * H_ + h0;
#pragma unroll 4
  for (int s = w * 128; s < w * 128 + 128; ++s) {
    bf16x4 v = *(const bf16x4*)(ep + (size_t)s * H_);
    float a = al[s];
    acc0 = fmaf(a, (float)v[0], acc0);
    acc1 = fmaf(a, (float)v[1], acc1);
    acc2 = fmaf(a, (float)v[2], acc2);
    acc3 = fmaf(a, (float)v[3], acc3);
  }
  part[w][lane * 4 + 0] = acc0;
  part[w][lane * 4 + 1] = acc1;
  part[w][lane * 4 + 2] = acc2;
  part[w][lane * 4 + 3] = acc3;
  __syncthreads();
  if (threadIdx.x < 256) {
    int o = threadIdx.x;
    if (o < 256)
      ctx[b * H_ + q * 256 + o] = part[0][o] + part[1][o] + part[2][o] + part[3][o];
  }
}

// ---------------- GRU with folded split-K partial reduction ----------------
__global__ __launch_bounds__(256)
void gru_kernel(const float* __restrict__ pgi, const float* __restrict__ pgh,
                const float* __restrict__ b_ih, const float* __restrict__ b_hh,
                const float* __restrict__ h_att, float* __restrict__ h_new_ws,
                float* __restrict__ out_h)
{
  int idx = blockIdx.x * 256 + threadIdx.x;  // B*H
  int b = idx >> 10, h = idx & 1023;
  float ir = b_ih[h], iz = b_ih[H_ + h], in_ = b_ih[2 * H_ + h];
  float hr = b_hh[h], hz = b_hh[H_ + h], hn = b_hh[2 * H_ + h];
#pragma unroll
  for (int p = 0; p < 8; ++p) {
    const float* gp = pgi + (size_t)p * 128 * 3072 + (size_t)b * 3072;
    ir += gp[h]; iz += gp[H_ + h]; in_ += gp[2 * H_ + h];
    const float* hp = pgh + (size_t)p * 128 * 3072 + (size_t)b * 3072;
    hr += hp[h]; hz += hp[H_ + h]; hn += hp[2 * H_ + h];
  }
  float r = 1.f / (1.f + expf(-(ir + hr)));
  float z = 1.f / (1.f + expf(-(iz + hz)));
  float n = tanhf(in_ + r * hn);
  float ha = h_att[(size_t)b * H_ + h];
  float hv = (1.f - z) * n + z * ha;
  h_new_ws[idx] = hv;
  out_h[idx] = hv;
}

__global__ __launch_bounds__(256)
void pgen_kernel(const float* __restrict__ context, const float* __restrict__ h_new,
                 const int* __restrict__ input, const float* __restrict__ emb,
                 const float* __restrict__ wgen_w, const float* __restrict__ wgen_b,
                 float* __restrict__ pgen)
{
  int b = blockIdx.x;
  const float* erow = emb + (size_t)input[b] * F_;
  float acc = 0.f;
  for (int j = threadIdx.x; j < H_; j += 256) acc = fmaf(context[b * H_ + j], wgen_w[j], acc);
  for (int j = threadIdx.x; j < H_; j += 256) acc = fmaf(h_new[b * H_ + j], wgen_w[H_ + j], acc);
  for (int j = threadIdx.x; j < F_; j += 256) acc = fmaf(erow[j], wgen_w[2 * H_ + j], acc);
  __shared__ float red[256];
  red[threadIdx.x] = acc;
  __syncthreads();
  for (int st = 128; st > 0; st >>= 1) {
    if (threadIdx.x < st) red[threadIdx.x] += red[threadIdx.x + st];
    __syncthreads();
  }
  if (threadIdx.x == 0) {
    float p = 1.f / (1.f + expf(-(red[0] + wgen_b[0])));
    p = fminf(fmaxf(p, 0.001f), 0.999f);
    pgen[b] = p;
  }
}

__global__ __launch_bounds__(512)
void vstats_kernel(const float* __restrict__ logits, float* __restrict__ vmax,
                   float* __restrict__ vsum)
{
  int b = blockIdx.x;
  const float* row = logits + (size_t)b * EV_;
  __shared__ float red[512];
  float m = -1e30f;
  for (int v = threadIdx.x; v < V_; v += 512) m = fmaxf(m, row[v]);
  red[threadIdx.x] = m;
  __syncthreads();
  for (int st = 256; st > 0; st >>= 1) {
    if (threadIdx.x < st) red[threadIdx.x] = fmaxf(red[threadIdx.x], red[threadIdx.x + st]);
    __syncthreads();
  }
  m = red[0];
  __syncthreads();
  float ssum = 0.f;
  for (int v = threadIdx.x; v < V_; v += 512) ssum += expf(row[v] - m);
  red[threadIdx.x] = ssum;
  __syncthreads();
  for (int st = 256; st > 0; st >>= 1) {
    if (threadIdx.x < st) red[threadIdx.x] += red[threadIdx.x + st];
    __syncthreads();
  }
  if (threadIdx.x == 0) { vmax[b] = m; vsum[b] = red[0]; }
}

__global__ void final_kernel(float* __restrict__ out0, const float* __restrict__ vmax,
                             const float* __restrict__ vsum, const float* __restrict__ pgen)
{
  int b = blockIdx.y;
  int v = blockIdx.x * 256 + threadIdx.x;
  if (v >= EV_) return;
  float* row = out0 + (size_t)b * EV_;
  if (v < V_) row[v] = pgen[b] * expf(row[v] - vmax[b]) / vsum[b];
  else row[v] = 0.f;
}

__global__ void scatter_kernel(const int* __restrict__ ref2tgt, const float* __restrict__ a_ws,
                               const float* __restrict__ pgen, float* __restrict__ out0)
{
  int b = blockIdx.x;
  int s = threadIdx.x;
  float w = (1.f - pgen[b]) * a_ws[b * S_ + s];
  int t = ref2tgt[b * S_ + s];
  atomicAdd(&out0[(size_t)b * EV_ + t], w);
}

extern "C" void kernel_launch(void* const* d_in, const int* in_sizes, int n_in,
                              void* d_out, int out_size, void* d_ws, size_t ws_size,
                              hipStream_t stream)
{
  const int*   input   = (const int*)d_in[0];
  const float* hidden  = (const float*)d_in[1];
  const float* enc     = (const float*)d_in[2];
  const float* mask    = (const float*)d_in[3];
  const float* cov     = (const float*)d_in[5];
  const int*   ref2tgt = (const int*)d_in[6];
  const float* emb     = (const float*)d_in[7];
  const float* W_ih    = (const float*)d_in[8];
  const float* W_hh    = (const float*)d_in[9];
  const float* b_ih    = (const float*)d_in[10];
  const float* b_hh    = (const float*)d_in[11];
  const float* e2v1_w  = (const float*)d_in[12];
  const float* e2v1_b  = (const float*)d_in[13];
  const float* e2v2_w  = (const float*)d_in[14];
  const float* e2v2_b  = (const float*)d_in[15];
  const float* fc_w    = (const float*)d_in[16];
  const float* fc_b    = (const float*)d_in[17];
  const float* wgen_w  = (const float*)d_in[18];
  const float* wgen_b  = (const float*)d_in[19];
  const float* att_Wh  = (const float*)d_in[20];
  const float* att_Ws  = (const float*)d_in[21];
  const float* att_wc  = (const float*)d_in[22];
  const float* att_b   = (const float*)d_in[23];
  const float* att_v   = (const float*)d_in[24];

  char* w = (char*)d_ws;
  __bf16* enc_h  = (__bf16*)w;  w += (size_t)B_ * S_ * H_ * 2;   // 134.2 MB
  __bf16* Wh_h   = (__bf16*)w;  w += (size_t)H_ * H_ * 2;        // 2 MB
  __bf16* out1_h = (__bf16*)w;  w += (size_t)B_ * F_ * 2;
  float* e_part  = (float*)w;   w += (size_t)8 * B_ * S_ * 4;
  float* a_ws    = (float*)w;   w += (size_t)B_ * S_ * 4;
  float* context = (float*)w;   w += (size_t)B_ * H_ * 4;
  float* h_att   = (float*)w;   w += (size_t)B_ * H_ * 4;
  float* h_new   = (float*)w;   w += (size_t)B_ * H_ * 4;
  float* pgen    = (float*)w;   w += 128 * 4;
  float* vmax    = (float*)w;   w += 128 * 4;
  float* vsum    = (float*)w;   w += 128 * 4;
  float* pA      = (float*)w;   w += (size_t)16 * 128 * 1024 * 4;  // 8 MB (sWs / fc / out1)
  float* pB      = (float*)w;   w += (size_t)8 * 128 * 3072 * 4;   // 12.6 MB (gi)
  float* pC      = (float*)w;   w += (size_t)8 * 128 * 3072 * 4;   // 12.6 MB (gh)

  float* out0    = (float*)d_out;
  float* out_h   = out0 + (size_t)B_ * EV_;
  float* out_cov = out_h + (size_t)B_ * H_;
  float* out_a   = out_cov + (size_t)B_ * S_;

  // 1. combined bf16 casts (enc + Wh)
  cast_both_kernel<<<4096, 256, 0, stream>>>(enc, enc_h, att_Wh, Wh_h);
  // 2. sWs split-K partials (reduction folded into feat epilogue)
  gemm_splitk<<<dim3(32, 16), 256, 0, stream>>>(hidden, att_Ws, pA, H_, H_, 64);
  // 3. fused attention feature GEMM
  feat_mfma_kernel<<<dim3(4096), 256, 0, stream>>>(enc_h, Wh_h, pA, cov, att_wc, att_b, att_v, e_part);
  // 4. softmax + coverage
  softmax_a_kernel<<<B_, 512, 0, stream>>>(e_part, mask, cov, a_ws, out_a, out_cov);
  // 5. context from bf16 enc
  context_kernel<<<dim3(4, B_), 256, 0, stream>>>(a_ws, enc_h, context);
  // 6. h_att = [hidden, context] @ fc_w^T + fc_b
  gemm_splitk_cat<<<dim3(32, 16), 256, 0, stream>>>(hidden, context, fc_w, pA, H_, 2 * H_, 128);
  reduce_partial<<<512, 256, 0, stream>>>(pA, fc_b, h_att, H_, 16);
  // 7. GRU gate partials (reductions folded into gru)
  gemm_splitk_gather<<<dim3(96, 8), 256, 0, stream>>>(input, emb, W_ih, pB, 3 * H_, F_, 64);
  gemm_splitk<<<dim3(96, 8), 256, 0, stream>>>(h_att, W_hh, pC, 3 * H_, H_, 128);
  gru_kernel<<<(B_ * H_) / 256, 256, 0, stream>>>(pB, pC, b_ih, b_hh, h_att, h_new, out_h);
  // 8. out1 = h_new @ e2v1^T + b  (reduce straight to bf16)
  gemm_splitk<<<dim3(16, 16), 256, 0, stream>>>(h_new, e2v1_w, pA, F_, H_, 64);
  reduce_partial_bf16<<<256, 256, 0, stream>>>(pA, e2v1_b, out1_h, F_, 16);
  // 9. vocab logits + softmax + pointer mix
  logits_mfma_kernel<<<dim3((V_ + BN - 1) / BN), 256, 0, stream>>>(out1_h, e2v2_w, e2v2_b, out0);
  pgen_kernel<<<B_, 256, 0, stream>>>(context, h_new, input, emb, wgen_w, wgen_b, pgen);
  vstats_kernel<<<B_, 512, 0, stream>>>(out0, vmax, vsum);
  final_kernel<<<dim3((EV_ + 255) / 256, B_), 256, 0, stream>>>(out0, vmax, vsum, pgen);
  scatter_kernel<<<B_, 512, 0, stream>>>(ref2tgt, a_ws, pgen, out0);
}

// Round 5
// 500.341 us; speedup vs baseline: 12.9484x; 1.0489x over previous
//
#include <hip/hip_runtime.h>
#include <math.h>

#define B_   128
#define S_   512
#define H_   1024
#define F_   512
#define V_   50000
#define OOV_ 50
#define EV_  (V_ + OOV_)   // 50050

#define BM 128
#define BN 128
#define BK 64

// 256^2 feat tile
#define BM2 256
#define BN2 256
#define BK2 64

typedef __attribute__((ext_vector_type(8))) __bf16 bf16x8;
typedef __attribute__((ext_vector_type(4))) __bf16 bf16x4;
typedef __attribute__((ext_vector_type(4))) float  f32x4;

__device__ __forceinline__ void gload_lds16(const void* g, void* lds) {
  __builtin_amdgcn_global_load_lds(
      (const __attribute__((address_space(1))) unsigned int*)g,
      (__attribute__((address_space(3))) unsigned int*)lds, 16, 0, 0);
}

__device__ __forceinline__ float fast_tanh(float x) {
  float v = fminf(fmaxf(x, -15.f), 15.f);
  float t = __expf(2.f * v);
  return 1.f - 2.f / (t + 1.f);
}

// ---------------- combined fp32 -> bf16 cast: enc then Wh ----------------
__global__ __launch_bounds__(256)
void cast_both_kernel(const float* __restrict__ enc, __bf16* __restrict__ enc_h,
                      const float* __restrict__ wh, __bf16* __restrict__ wh_h)
{
  const size_t n_enc = (size_t)B_ * S_ * H_;
  const size_t n_tot = n_enc + (size_t)H_ * H_;
  for (size_t i = ((size_t)blockIdx.x * 256 + threadIdx.x) * 8; i < n_tot;
       i += (size_t)gridDim.x * 256 * 8) {
    const float* in; __bf16* out; size_t j;
    if (i < n_enc) { in = enc; out = enc_h; j = i; }
    else           { in = wh;  out = wh_h;  j = i - n_enc; }
    float4 a = *(const float4*)(in + j);
    float4 b = *(const float4*)(in + j + 4);
    bf16x8 o;
    o[0] = (__bf16)a.x; o[1] = (__bf16)a.y; o[2] = (__bf16)a.z; o[3] = (__bf16)a.w;
    o[4] = (__bf16)b.x; o[5] = (__bf16)b.y; o[6] = (__bf16)b.z; o[7] = (__bf16)b.w;
    *(bf16x8*)(out + j) = o;
  }
}

// ---------------- split-K fp32 GEMM core ----------------
__global__ __launch_bounds__(256)
void gemm_splitk(const float* __restrict__ A, const float* __restrict__ W,
                 float* __restrict__ partial, int N, int K, int KS)
{
  __shared__ float As[128 * 68];
  __shared__ float Ws[32 * 68];
  const int tid = threadIdx.x;
  const int n0 = blockIdx.x * 32;
  const int p  = blockIdx.y;
  const int tx = tid & 7, ty = tid >> 3;
  const int lr = tid >> 4, lc4 = (tid & 15) * 4;
  float acc[4][4] = {};
  const int kend = p * KS + KS;
  for (int k0 = p * KS; k0 < kend; k0 += 64) {
#pragma unroll
    for (int pp = 0; pp < 8; ++pp)
      *(float4*)(As + (pp * 16 + lr) * 68 + lc4) =
          *(const float4*)(A + (size_t)(pp * 16 + lr) * K + k0 + lc4);
#pragma unroll
    for (int pp = 0; pp < 2; ++pp)
      *(float4*)(Ws + (pp * 16 + lr) * 68 + lc4) =
          *(const float4*)(W + (size_t)(n0 + pp * 16 + lr) * K + k0 + lc4);
    __syncthreads();
#pragma unroll
    for (int kk = 0; kk < 16; ++kk) {
      float4 av[4], wv[4];
#pragma unroll
      for (int i = 0; i < 4; i++) av[i] = *(const float4*)(As + (ty * 4 + i) * 68 + kk * 4);
#pragma unroll
      for (int j = 0; j < 4; j++) wv[j] = *(const float4*)(Ws + (tx * 4 + j) * 68 + kk * 4);
#pragma unroll
      for (int i = 0; i < 4; i++)
#pragma unroll
        for (int j = 0; j < 4; j++) {
          acc[i][j] = fmaf(av[i].x, wv[j].x, acc[i][j]);
          acc[i][j] = fmaf(av[i].y, wv[j].y, acc[i][j]);
          acc[i][j] = fmaf(av[i].z, wv[j].z, acc[i][j]);
          acc[i][j] = fmaf(av[i].w, wv[j].w, acc[i][j]);
        }
    }
    __syncthreads();
  }
#pragma unroll
  for (int i = 0; i < 4; i++)
#pragma unroll
    for (int j = 0; j < 4; j++)
      partial[((size_t)p * 128 + ty * 4 + i) * N + n0 + tx * 4 + j] = acc[i][j];
}

// variant: A = concat(A1[128,1024], A2[128,1024]) along K (KS=128 keeps p in one half)
__global__ __launch_bounds__(256)
void gemm_splitk_cat(const float* __restrict__ A1, const float* __restrict__ A2,
                     const float* __restrict__ W, float* __restrict__ partial,
                     int N, int K, int KS)
{
  __shared__ float As[128 * 68];
  __shared__ float Ws[32 * 68];
  const int tid = threadIdx.x;
  const int n0 = blockIdx.x * 32;
  const int p  = blockIdx.y;
  const int tx = tid & 7, ty = tid >> 3;
  const int lr = tid >> 4, lc4 = (tid & 15) * 4;
  const float* A = (p * KS < 1024) ? A1 : A2;
  const int kbase = (p * KS < 1024) ? 0 : 1024;
  float acc[4][4] = {};
  const int kend = p * KS + KS;
  for (int k0 = p * KS; k0 < kend; k0 += 64) {
#pragma unroll
    for (int pp = 0; pp < 8; ++pp)
      *(float4*)(As + (pp * 16 + lr) * 68 + lc4) =
          *(const float4*)(A + (size_t)(pp * 16 + lr) * 1024 + (k0 - kbase) + lc4);
#pragma unroll
    for (int pp = 0; pp < 2; ++pp)
      *(float4*)(Ws + (pp * 16 + lr) * 68 + lc4) =
          *(const float4*)(W + (size_t)(n0 + pp * 16 + lr) * K + k0 + lc4);
    __syncthreads();
#pragma unroll
    for (int kk = 0; kk < 16; ++kk) {
      float4 av[4], wv[4];
#pragma unroll
      for (int i = 0; i < 4; i++) av[i] = *(const float4*)(As + (ty * 4 + i) * 68 + kk * 4);
#pragma unroll
      for (int j = 0; j < 4; j++) wv[j] = *(const float4*)(Ws + (tx * 4 + j) * 68 + kk * 4);
#pragma unroll
      for (int i = 0; i < 4; i++)
#pragma unroll
        for (int j = 0; j < 4; j++) {
          acc[i][j] = fmaf(av[i].x, wv[j].x, acc[i][j]);
          acc[i][j] = fmaf(av[i].y, wv[j].y, acc[i][j]);
          acc[i][j] = fmaf(av[i].z, wv[j].z, acc[i][j]);
          acc[i][j] = fmaf(av[i].w, wv[j].w, acc[i][j]);
        }
    }
    __syncthreads();
  }
#pragma unroll
  for (int i = 0; i < 4; i++)
#pragma unroll
    for (int j = 0; j < 4; j++)
      partial[((size_t)p * 128 + ty * 4 + i) * N + n0 + tx * 4 + j] = acc[i][j];
}

// variant: A rows gathered from emb via input[]
__global__ __launch_bounds__(256)
void gemm_splitk_gather(const int* __restrict__ input, const float* __restrict__ emb,
                        const float* __restrict__ W, float* __restrict__ partial,
                        int N, int K, int KS)
{
  __shared__ float As[128 * 68];
  __shared__ float Ws[32 * 68];
  const int tid = threadIdx.x;
  const int n0 = blockIdx.x * 32;
  const int p  = blockIdx.y;
  const int tx = tid & 7, ty = tid >> 3;
  const int lr = tid >> 4, lc4 = (tid & 15) * 4;
  float acc[4][4] = {};
  const int kend = p * KS + KS;
  for (int k0 = p * KS; k0 < kend; k0 += 64) {
#pragma unroll
    for (int pp = 0; pp < 8; ++pp) {
      int row = input[pp * 16 + lr];
      *(float4*)(As + (pp * 16 + lr) * 68 + lc4) =
          *(const float4*)(emb + (size_t)row * K + k0 + lc4);
    }
#pragma unroll
    for (int pp = 0; pp < 2; ++pp)
      *(float4*)(Ws + (pp * 16 + lr) * 68 + lc4) =
          *(const float4*)(W + (size_t)(n0 + pp * 16 + lr) * K + k0 + lc4);
    __syncthreads();
#pragma unroll
    for (int kk = 0; kk < 16; ++kk) {
      float4 av[4], wv[4];
#pragma unroll
      for (int i = 0; i < 4; i++) av[i] = *(const float4*)(As + (ty * 4 + i) * 68 + kk * 4);
#pragma unroll
      for (int j = 0; j < 4; j++) wv[j] = *(const float4*)(Ws + (tx * 4 + j) * 68 + kk * 4);
#pragma unroll
      for (int i = 0; i < 4; i++)
#pragma unroll
        for (int j = 0; j < 4; j++) {
          acc[i][j] = fmaf(av[i].x, wv[j].x, acc[i][j]);
          acc[i][j] = fmaf(av[i].y, wv[j].y, acc[i][j]);
          acc[i][j] = fmaf(av[i].z, wv[j].z, acc[i][j]);
          acc[i][j] = fmaf(av[i].w, wv[j].w, acc[i][j]);
        }
    }
    __syncthreads();
  }
#pragma unroll
  for (int i = 0; i < 4; i++)
#pragma unroll
    for (int j = 0; j < 4; j++)
      partial[((size_t)p * 128 + ty * 4 + i) * N + n0 + tx * 4 + j] = acc[i][j];
}

__global__ __launch_bounds__(256)
void reduce_partial(const float* __restrict__ partial, const float* __restrict__ bias,
                    float* __restrict__ C, int N, int P)
{
  int idx = blockIdx.x * 256 + threadIdx.x;
  int n = idx % N;
  float s = bias ? bias[n] : 0.f;
  for (int p = 0; p < P; ++p) s += partial[(size_t)p * 128 * N + idx];
  C[idx] = s;
}

__global__ __launch_bounds__(256)
void reduce_partial_bf16(const float* __restrict__ partial, const float* __restrict__ bias,
                         __bf16* __restrict__ C, int N, int P)
{
  int idx = blockIdx.x * 256 + threadIdx.x;
  int n = idx % N;
  float s = bias ? bias[n] : 0.f;
  for (int p = 0; p < P; ++p) s += partial[(size_t)p * 128 * N + idx];
  C[idx] = (__bf16)s;
}

// ------------- 256^2 2-phase dbuf MFMA attention feature GEMM + fused tanh·v reduce -------------
// e_part[nt][bs] = sum_{n in nt-tile of 256} tanh(enc·Wh^T + sWs + cov*wc + ab)[bs,n] * av[n]
__global__ __launch_bounds__(512, 2)
void feat_mfma256_kernel(const __bf16* __restrict__ enc, const __bf16* __restrict__ Wh,
                         const float* __restrict__ sws, const float* __restrict__ cov,
                         const float* __restrict__ wcv, const float* __restrict__ ab,
                         const float* __restrict__ av_, float* __restrict__ e_part)
{
  // 64 KB A dbuf + 64 KB B dbuf = 128 KB (fits 160 KB LDS/CU; 1 block/CU)
  __shared__ __attribute__((aligned(16))) __bf16 As[2][BM2 * BK2];
  __shared__ __attribute__((aligned(16))) __bf16 Bs[2][BN2 * BK2];
  const int tid  = threadIdx.x;
  const int lane = tid & 63, wid = tid >> 6;   // 8 waves
  const int wr = wid >> 2, wc = wid & 3;       // 2 x 4 wave grid; wave owns 128x64
  // bijective XCD-chunked swizzle (nwg=1024, 8|1024): n-tile cycles fastest so the
  // 4 n-blocks of one A-panel run on the same XCD; Wh (2 MB bf16) stays L2-resident.
  const int bid = blockIdx.x;
  const int swz = (bid & 7) * 128 + (bid >> 3);
  const int mt = swz >> 2, nt = swz & 3;
  const int bs0 = mt * BM2;
  const int n0  = nt * BN2;
  const int b   = bs0 >> 9;   // bs0/S_; 256-row tile lies within one batch row

  f32x4 acc[8][4];
#pragma unroll
  for (int i = 0; i < 8; i++)
#pragma unroll
    for (int j = 0; j < 4; j++) acc[i][j] = (f32x4){0.f, 0.f, 0.f, 0.f};

#define STAGE2(c, k0)                                                          \
  {                                                                            \
    _Pragma("unroll")                                                          \
    for (int p = 0; p < 4; ++p) {                                              \
      int off = p * 8192 + tid * 16;                                           \
      int r = off >> 7, cb = off & 127;                                        \
      int scb = cb ^ ((r & 7) << 4);                                           \
      gload_lds16(enc + (size_t)(bs0 + r) * H_ + (k0) + (scb >> 1),            \
                  (char*)As[c] + off);                                         \
      gload_lds16(Wh + (size_t)(n0 + r) * H_ + (k0) + (scb >> 1),              \
                  (char*)Bs[c] + off);                                         \
    }                                                                          \
  }

  // prologue: stage first K-tile
  STAGE2(0, 0)
  __syncthreads();   // vmcnt(0) drain + barrier

  int cur = 0;
  for (int kt = 0; kt < 16; ++kt) {
    // issue next-tile prefetch FIRST: its HBM latency hides under ds_read+MFMA below
    if (kt < 15) STAGE2(cur ^ 1, (kt + 1) * BK2)

    // B fragments for this wave's 64 cols (4 n-frags x 2 k-halves)
    bf16x8 bfv[4][2];
#pragma unroll
    for (int n = 0; n < 4; ++n) {
      int row = wc * 64 + n * 16 + (lane & 15);
      int sw = (row & 7) << 4;
#pragma unroll
      for (int kk = 0; kk < 2; ++kk) {
        int kb = kk * 64 + ((lane >> 4) << 4);
        bfv[n][kk] = *(const bf16x8*)((const char*)Bs[cur] + row * 128 + (kb ^ sw));
      }
    }
    // A fragments streamed per m-row-block (8 x 2 reads), 64 MFMA total
#pragma unroll
    for (int m = 0; m < 8; ++m) {
      int row = wr * 128 + m * 16 + (lane & 15);
      int sw = (row & 7) << 4;
      bf16x8 af[2];
#pragma unroll
      for (int kk = 0; kk < 2; ++kk) {
        int kb = kk * 64 + ((lane >> 4) << 4);
        af[kk] = *(const bf16x8*)((const char*)As[cur] + row * 128 + (kb ^ sw));
      }
#pragma unroll
      for (int n = 0; n < 4; ++n)
#pragma unroll
        for (int kk = 0; kk < 2; ++kk)
          acc[m][n] = __builtin_amdgcn_mfma_f32_16x16x32_bf16(af[kk], bfv[n][kk], acc[m][n], 0, 0, 0);
    }
    __syncthreads();   // drains prefetch vmcnt + lgkm; next tile ready
    cur ^= 1;
  }
#undef STAGE2

  // epilogue: + sWs + cov*wc + ab, fast-tanh, *av, reduce over this tile's 256 cols
  float rowsum[8][4];
#pragma unroll
  for (int m = 0; m < 8; m++)
#pragma unroll
    for (int j = 0; j < 4; j++) rowsum[m][j] = 0.f;

#pragma unroll
  for (int n = 0; n < 4; ++n) {
    int col_g = n0 + wc * 64 + n * 16 + (lane & 15);
    float sw   = sws[(size_t)b * H_ + col_g];
    float wc_n = wcv[col_g], ab_n = ab[col_g], av_n = av_[col_g];
#pragma unroll
    for (int m = 0; m < 8; ++m) {
#pragma unroll
      for (int j = 0; j < 4; ++j) {
        int row_l = wr * 128 + m * 16 + ((lane >> 4) << 2) + j;
        float val = acc[m][n][j] + sw + cov[bs0 + row_l] * wc_n + ab_n;
        rowsum[m][j] += fast_tanh(val) * av_n;
      }
    }
  }
  // sum across the 16 lanes holding different columns of the same row
#pragma unroll
  for (int m = 0; m < 8; ++m)
#pragma unroll
    for (int j = 0; j < 4; ++j) {
      float v = rowsum[m][j];
      v += __shfl_xor(v, 1);
      v += __shfl_xor(v, 2);
      v += __shfl_xor(v, 4);
      v += __shfl_xor(v, 8);
      rowsum[m][j] = v;
    }
  // cross-wave reduce over the 4 wc groups via LDS (reuse dead As space)
  float (*red)[4] = (float(*)[4])As;   // 256 x 4 floats = 4 KB
  if ((lane & 15) == 0) {
#pragma unroll
    for (int m = 0; m < 8; ++m)
#pragma unroll
      for (int j = 0; j < 4; ++j)
        red[wr * 128 + m * 16 + ((lane >> 4) << 2) + j][wc] = rowsum[m][j];
  }
  __syncthreads();
  if (tid < BM2)
    e_part[(size_t)nt * (B_ * S_) + bs0 + tid] =
        red[tid][0] + red[tid][1] + red[tid][2] + red[tid][3];
}

// ------------- MFMA logits GEMM -------------
__global__ __launch_bounds__(256)
void logits_mfma_kernel(const __bf16* __restrict__ A, const float* __restrict__ W,
                        const float* __restrict__ bias, float* __restrict__ out0)
{
  __shared__ __attribute__((aligned(16))) __bf16 As[BM * BK];
  __shared__ __attribute__((aligned(16))) __bf16 Bs[BN * BK];
  const int tid  = threadIdx.x;
  const int lane = tid & 63, wid = tid >> 6;
  const int wr = wid >> 1, wcc = wid & 1;
  const int n0 = blockIdx.x * BN;

  f32x4 acc[4][4];
#pragma unroll
  for (int i = 0; i < 4; i++)
#pragma unroll
    for (int j = 0; j < 4; j++) acc[i][j] = (f32x4){0.f, 0.f, 0.f, 0.f};

  for (int k0 = 0; k0 < F_; k0 += BK) {
#pragma unroll
    for (int p = 0; p < 4; ++p) {
      int off = p * 4096 + tid * 16;
      int r = off >> 7, cb = off & 127;
      int scb = cb ^ ((r & 7) << 4);
      gload_lds16(A + (size_t)r * F_ + k0 + (scb >> 1), (char*)As + off);
    }
#pragma unroll
    for (int p = 0; p < 8; ++p) {
      int idx = p * 1024 + tid * 4;
      int r = idx >> 6, c = idx & 63;
      int row_g = n0 + r; if (row_g >= V_) row_g = V_ - 1;
      float4 f = *(const float4*)(W + (size_t)row_g * F_ + k0 + c);
      union { __bf16 h[4]; uint2 u; } t;
      t.h[0] = (__bf16)f.x; t.h[1] = (__bf16)f.y; t.h[2] = (__bf16)f.z; t.h[3] = (__bf16)f.w;
      int cb = c * 2;
      *(uint2*)((char*)Bs + r * 128 + (cb ^ ((r & 7) << 4))) = t.u;
    }
    __syncthreads();

    bf16x8 af[4][2], bfv[4][2];
#pragma unroll
    for (int m = 0; m < 4; ++m) {
      int row = wr * 64 + m * 16 + (lane & 15);
      int swz = (row & 7) << 4;
#pragma unroll
      for (int kk = 0; kk < 2; ++kk) {
        int kb = kk * 64 + ((lane >> 4) << 4);
        af[m][kk] = *(const bf16x8*)((const char*)As + row * 128 + (kb ^ swz));
      }
    }
#pragma unroll
    for (int n = 0; n < 4; ++n) {
      int row = wcc * 64 + n * 16 + (lane & 15);
      int swz = (row & 7) << 4;
#pragma unroll
      for (int kk = 0; kk < 2; ++kk) {
        int kb = kk * 64 + ((lane >> 4) << 4);
        bfv[n][kk] = *(const bf16x8*)((const char*)Bs + row * 128 + (kb ^ swz));
      }
    }
#pragma unroll
    for (int m = 0; m < 4; ++m)
#pragma unroll
      for (int n = 0; n < 4; ++n)
#pragma unroll
        for (int kk = 0; kk < 2; ++kk)
          acc[m][n] = __builtin_amdgcn_mfma_f32_16x16x32_bf16(af[m][kk], bfv[n][kk], acc[m][n], 0, 0, 0);
    __syncthreads();
  }

#pragma unroll
  for (int m = 0; m < 4; ++m) {
#pragma unroll
    for (int n = 0; n < 4; ++n) {
      int col_g = n0 + wcc * 64 + n * 16 + (lane & 15);
      if (col_g >= V_) continue;
      float bv = bias[col_g];
#pragma unroll
      for (int j = 0; j < 4; ++j) {
        int row = wr * 64 + m * 16 + ((lane >> 4) << 2) + j;
        out0[(size_t)row * EV_ + col_g] = acc[m][n][j] + bv;
      }
    }
  }
}

// ---------------- softmax over S + renorm + coverage ----------------
__global__ __launch_bounds__(512)
void softmax_a_kernel(const float* __restrict__ e_part, const float* __restrict__ mask,
                      const float* __restrict__ cov, float* __restrict__ a_ws,
                      float* __restrict__ out_a, float* __restrict__ out_cov)
{
  const int b = blockIdx.x;
  const int s = threadIdx.x;
  __shared__ float red[512];
  float e = 0.f;
  for (int kt = 0; kt < 4; ++kt) e += e_part[(size_t)kt * (B_ * S_) + b * S_ + s];
  red[s] = e;
  __syncthreads();
  for (int st = 256; st > 0; st >>= 1) {
    if (s < st) red[s] = fmaxf(red[s], red[s + st]);
    __syncthreads();
  }
  float mx = red[0];
  __syncthreads();
  float ex = expf(e - mx) * mask[b * S_ + s];
  red[s] = ex;
  __syncthreads();
  for (int st = 256; st > 0; st >>= 1) {
    if (s < st) red[s] += red[s + st];
    __syncthreads();
  }
  float a = ex / red[0];
  a_ws[b * S_ + s] = a;
  out_a[b * S_ + s] = a;
  out_cov[b * S_ + s] = cov[b * S_ + s] + a;
}

// ---------------- context[b,h] = sum_s a[b,s] * enc_h[b,s,h]  (bf16 enc) ----------------
__global__ __launch_bounds__(256)
void context_kernel(const float* __restrict__ a_ws, const __bf16* __restrict__ enc,
                    float* __restrict__ ctx)
{
  const int b = blockIdx.y, q = blockIdx.x;
  const int lane = threadIdx.x & 63, w = threadIdx.x >> 6;
  const int h0 = q * 256 + lane * 4;
  __shared__ float al[S_];
  __shared__ float part[4][256];
  for (int i = threadIdx.x; i < S_; i += 256) al[i] = a_ws[b * S_ + i];
  __syncthreads();
  float acc0 = 0.f, acc1 = 0.f, acc2 = 0.f, acc3 = 0.f;
  const __bf16* ep = enc + (size_t)b * S_ * H_ + h0;
#pragma unroll 4
  for (int s = w * 128; s < w * 128 + 128; ++s) {
    bf16x4 v = *(const bf16x4*)(ep + (size_t)s * H_);
    float a = al[s];
    acc0 = fmaf(a, (float)v[0], acc0);
    acc1 = fmaf(a, (float)v[1], acc1);
    acc2 = fmaf(a, (float)v[2], acc2);
    acc3 = fmaf(a, (float)v[3], acc3);
  }
  part[w][lane * 4 + 0] = acc0;
  part[w][lane * 4 + 1] = acc1;
  part[w][lane * 4 + 2] = acc2;
  part[w][lane * 4 + 3] = acc3;
  __syncthreads();
  if (threadIdx.x < 256) {
    int o = threadIdx.x;
    ctx[b * H_ + q * 256 + o] = part[0][o] + part[1][o] + part[2][o] + part[3][o];
  }
}

// ---------------- GRU with folded split-K partial reduction ----------------
__global__ __launch_bounds__(256)
void gru_kernel(const float* __restrict__ pgi, const float* __restrict__ pgh,
                const float* __restrict__ b_ih, const float* __restrict__ b_hh,
                const float* __restrict__ h_att, float* __restrict__ h_new_ws,
                float* __restrict__ out_h)
{
  int idx = blockIdx.x * 256 + threadIdx.x;
  int b = idx >> 10, h = idx & 1023;
  float ir = b_ih[h], iz = b_ih[H_ + h], in_ = b_ih[2 * H_ + h];
  float hr = b_hh[h], hz = b_hh[H_ + h], hn = b_hh[2 * H_ + h];
#pragma unroll
  for (int p = 0; p < 8; ++p) {
    const float* gp = pgi + (size_t)p * 128 * 3072 + (size_t)b * 3072;
    ir += gp[h]; iz += gp[H_ + h]; in_ += gp[2 * H_ + h];
    const float* hp = pgh + (size_t)p * 128 * 3072 + (size_t)b * 3072;
    hr += hp[h]; hz += hp[H_ + h]; hn += hp[2 * H_ + h];
  }
  float r = 1.f / (1.f + expf(-(ir + hr)));
  float z = 1.f / (1.f + expf(-(iz + hz)));
  float n = tanhf(in_ + r * hn);
  float ha = h_att[(size_t)b * H_ + h];
  float hv = (1.f - z) * n + z * ha;
  h_new_ws[idx] = hv;
  out_h[idx] = hv;
}

__global__ __launch_bounds__(256)
void pgen_kernel(const float* __restrict__ context, const float* __restrict__ h_new,
                 const int* __restrict__ input, const float* __restrict__ emb,
                 const float* __restrict__ wgen_w, const float* __restrict__ wgen_b,
                 float* __restrict__ pgen)
{
  int b = blockIdx.x;
  const float* erow = emb + (size_t)input[b] * F_;
  float acc = 0.f;
  for (int j = threadIdx.x; j < H_; j += 256) acc = fmaf(context[b * H_ + j], wgen_w[j], acc);
  for (int j = threadIdx.x; j < H_; j += 256) acc = fmaf(h_new[b * H_ + j], wgen_w[H_ + j], acc);
  for (int j = threadIdx.x; j < F_; j += 256) acc = fmaf(erow[j], wgen_w[2 * H_ + j], acc);
  __shared__ float red[256];
  red[threadIdx.x] = acc;
  __syncthreads();
  for (int st = 128; st > 0; st >>= 1) {
    if (threadIdx.x < st) red[threadIdx.x] += red[threadIdx.x + st];
    __syncthreads();
  }
  if (threadIdx.x == 0) {
    float p = 1.f / (1.f + expf(-(red[0] + wgen_b[0])));
    p = fminf(fmaxf(p, 0.001f), 0.999f);
    pgen[b] = p;
  }
}

__global__ __launch_bounds__(512)
void vstats_kernel(const float* __restrict__ logits, float* __restrict__ vmax,
                   float* __restrict__ vsum)
{
  int b = blockIdx.x;
  const float* row = logits + (size_t)b * EV_;
  __shared__ float red[512];
  float m = -1e30f;
  for (int v = threadIdx.x; v < V_; v += 512) m = fmaxf(m, row[v]);
  red[threadIdx.x] = m;
  __syncthreads();
  for (int st = 256; st > 0; st >>= 1) {
    if (threadIdx.x < st) red[threadIdx.x] = fmaxf(red[threadIdx.x], red[threadIdx.x + st]);
    __syncthreads();
  }
  m = red[0];
  __syncthreads();
  float ssum = 0.f;
  for (int v = threadIdx.x; v < V_; v += 512) ssum += expf(row[v] - m);
  red[threadIdx.x] = ssum;
  __syncthreads();
  for (int st = 256; st > 0; st >>= 1) {
    if (threadIdx.x < st) red[threadIdx.x] += red[threadIdx.x + st];
    __syncthreads();
  }
  if (threadIdx.x == 0) { vmax[b] = m; vsum[b] = red[0]; }
}

__global__ void final_kernel(float* __restrict__ out0, const float* __restrict__ vmax,
                             const float* __restrict__ vsum, const float* __restrict__ pgen)
{
  int b = blockIdx.y;
  int v = blockIdx.x * 256 + threadIdx.x;
  if (v >= EV_) return;
  float* row = out0 + (size_t)b * EV_;
  if (v < V_) row[v] = pgen[b] * expf(row[v] - vmax[b]) / vsum[b];
  else row[v] = 0.f;
}

__global__ void scatter_kernel(const int* __restrict__ ref2tgt, const float* __restrict__ a_ws,
                               const float* __restrict__ pgen, float* __restrict__ out0)
{
  int b = blockIdx.x;
  int s = threadIdx.x;
  float w = (1.f - pgen[b]) * a_ws[b * S_ + s];
  int t = ref2tgt[b * S_ + s];
  atomicAdd(&out0[(size_t)b * EV_ + t], w);
}

extern "C" void kernel_launch(void* const* d_in, const int* in_sizes, int n_in,
                              void* d_out, int out_size, void* d_ws, size_t ws_size,
                              hipStream_t stream)
{
  const int*   input   = (const int*)d_in[0];
  const float* hidden  = (const float*)d_in[1];
  const float* enc     = (const float*)d_in[2];
  const float* mask    = (const float*)d_in[3];
  const float* cov     = (const float*)d_in[5];
  const int*   ref2tgt = (const int*)d_in[6];
  const float* emb     = (const float*)d_in[7];
  const float* W_ih    = (const float*)d_in[8];
  const float* W_hh    = (const float*)d_in[9];
  const float* b_ih    = (const float*)d_in[10];
  const float* b_hh    = (const float*)d_in[11];
  const float* e2v1_w  = (const float*)d_in[12];
  const float* e2v1_b  = (const float*)d_in[13];
  const float* e2v2_w  = (const float*)d_in[14];
  const float* e2v2_b  = (const float*)d_in[15];
  const float* fc_w    = (const float*)d_in[16];
  const float* fc_b    = (const float*)d_in[17];
  const float* wgen_w  = (const float*)d_in[18];
  const float* wgen_b  = (const float*)d_in[19];
  const float* att_Wh  = (const float*)d_in[20];
  const float* att_Ws  = (const float*)d_in[21];
  const float* att_wc  = (const float*)d_in[22];
  const float* att_b   = (const float*)d_in[23];
  const float* att_v   = (const float*)d_in[24];

  char* w = (char*)d_ws;
  __bf16* enc_h  = (__bf16*)w;  w += (size_t)B_ * S_ * H_ * 2;   // 134.2 MB
  __bf16* Wh_h   = (__bf16*)w;  w += (size_t)H_ * H_ * 2;        // 2 MB
  __bf16* out1_h = (__bf16*)w;  w += (size_t)B_ * F_ * 2;
  float* sws     = (float*)w;   w += (size_t)B_ * H_ * 4;        // reduced sWs
  float* e_part  = (float*)w;   w += (size_t)4 * B_ * S_ * 4;    // 4 n-tiles of 256
  float* a_ws    = (float*)w;   w += (size_t)B_ * S_ * 4;
  float* context = (float*)w;   w += (size_t)B_ * H_ * 4;
  float* h_att   = (float*)w;   w += (size_t)B_ * H_ * 4;
  float* h_new   = (float*)w;   w += (size_t)B_ * H_ * 4;
  float* pgen    = (float*)w;   w += 128 * 4;
  float* vmax    = (float*)w;   w += 128 * 4;
  float* vsum    = (float*)w;   w += 128 * 4;
  float* pA      = (float*)w;   w += (size_t)16 * 128 * 1024 * 4;  // 8 MB (sWs / fc / out1)
  float* pB      = (float*)w;   w += (size_t)8 * 128 * 3072 * 4;   // 12.6 MB (gi)
  float* pC      = (float*)w;   w += (size_t)8 * 128 * 3072 * 4;   // 12.6 MB (gh)

  float* out0    = (float*)d_out;
  float* out_h   = out0 + (size_t)B_ * EV_;
  float* out_cov = out_h + (size_t)B_ * H_;
  float* out_a   = out_cov + (size_t)B_ * S_;

  // 1. combined bf16 casts (enc + Wh)
  cast_both_kernel<<<4096, 256, 0, stream>>>(enc, enc_h, att_Wh, Wh_h);
  // 2. sWs = hidden @ att_Ws^T  (split-K + reduce)
  gemm_splitk<<<dim3(32, 16), 256, 0, stream>>>(hidden, att_Ws, pA, H_, H_, 64);
  reduce_partial<<<512, 256, 0, stream>>>(pA, nullptr, sws, H_, 16);
  // 3. fused attention feature GEMM (256^2 2-phase dbuf)
  feat_mfma256_kernel<<<dim3(1024), 512, 0, stream>>>(enc_h, Wh_h, sws, cov, att_wc, att_b, att_v, e_part);
  // 4. softmax + coverage
  softmax_a_kernel<<<B_, 512, 0, stream>>>(e_part, mask, cov, a_ws, out_a, out_cov);
  // 5. context from bf16 enc
  context_kernel<<<dim3(4, B_), 256, 0, stream>>>(a_ws, enc_h, context);
  // 6. h_att = [hidden, context] @ fc_w^T + fc_b
  gemm_splitk_cat<<<dim3(32, 16), 256, 0, stream>>>(hidden, context, fc_w, pA, H_, 2 * H_, 128);
  reduce_partial<<<512, 256, 0, stream>>>(pA, fc_b, h_att, H_, 16);
  // 7. GRU gate partials (reductions folded into gru)
  gemm_splitk_gather<<<dim3(96, 8), 256, 0, stream>>>(input, emb, W_ih, pB, 3 * H_, F_, 64);
  gemm_splitk<<<dim3(96, 8), 256, 0, stream>>>(h_att, W_hh, pC, 3 * H_, H_, 128);
  gru_kernel<<<(B_ * H_) / 256, 256, 0, stream>>>(pB, pC, b_ih, b_hh, h_att, h_new, out_h);
  // 8. out1 = h_new @ e2v1^T + b  (reduce straight to bf16)
  gemm_splitk<<<dim3(16, 16), 256, 0, stream>>>(h_new, e2v1_w, pA, F_, H_, 64);
  reduce_partial_bf16<<<256, 256, 0, stream>>>(pA, e2v1_b, out1_h, F_, 16);
  // 9. vocab logits + softmax + pointer mix
  logits_mfma_kernel<<<dim3((V_ + BN - 1) / BN), 256, 0, stream>>>(out1_h, e2v2_w, e2v2_b, out0);
  pgen_kernel<<<B_, 256, 0, stream>>>(context, h_new, input, emb, wgen_w, wgen_b, pgen);
  vstats_kernel<<<B_, 512, 0, stream>>>(out0, vmax, vsum);
  final_kernel<<<dim3((EV_ + 255) / 256, B_), 256, 0, stream>>>(out0, vmax, vsum, pgen);
  scatter_kernel<<<B_, 512, 0, stream>>>(ref2tgt, a_ws, pgen, out0);
}